// Round 1
// baseline (18938.435 us; speedup 1.0000x reference)
//
#include <hip/hip_runtime.h>
#include <math.h>

#define EPSV 1e-10f

// ---------------------------------------------------------------------------
// Weight staging: W is (K x 64) row-major in global. We store it transposed
// into LDS as Wt[j][K] (j = output feature = lane), with the float4 blocks of
// each row XOR-swizzled (block kb lands at kb ^ (j&7)) so that a wave reading
// lane-j's block kb hits all 32 banks at the optimal 8 dwords/bank.
// ---------------------------------------------------------------------------
template <int K>
__device__ __forceinline__ void load_wt_swz(float* dst, const float* __restrict__ W) {
  constexpr int NB = K / 4;
  for (int idx = threadIdx.x; idx < 64 * NB; idx += blockDim.x) {
    const int j = idx / NB;
    const int kb = idx % NB;
    float4 v;
    v.x = W[(4 * kb + 0) * 64 + j];
    v.y = W[(4 * kb + 1) * 64 + j];
    v.z = W[(4 * kb + 2) * 64 + j];
    v.w = W[(4 * kb + 3) * 64 + j];
    reinterpret_cast<float4*>(dst)[j * NB + (kb ^ (j & 7))] = v;
  }
}

__device__ __forceinline__ float dot4(float4 a, float4 b) {
  return a.x * b.x + a.y * b.y + a.z * b.z + a.w * b.w;
}

__device__ __forceinline__ float wave_sum(float t) {
#pragma unroll
  for (int off = 32; off > 0; off >>= 1) t += __shfl_xor(t, off, 64);
  return t;
}

// ---------------------------------------------------------------------------
// Kernel 1: fused item-aggregation (both I-branch and S-branch).
// For each group (a (b) or a (b,q)):
//   rows p: x = MLP_gv(concat(item_emb, rate_emb))        (128->64->64)
//           logit = MLP_atti(concat(x, mask*u_emb))       (128->64->1)
//   e = exp(logit)*mask;  c = sum(e*x)/(sum(e)+EPS)
//   out = relu(c @ agg_W + agg_b)
// One block = groups_per_block consecutive groups. Block = 512 threads.
// Rows are processed in chunks of <=40; each wave owns rows wave+8i (i<5),
// interleaved so one weight ds_read_b128 feeds 5 rows (20 FMAs).
// ---------------------------------------------------------------------------
__global__ __launch_bounds__(512) void agg_kernel(
    const int groups_per_block, const int n_items,
    const int* __restrict__ ids,      // [group][item][2] (item_id, rate_id)
    const int* __restrict__ uid_arr,  // [group] -> user id
    const float* __restrict__ user_table, const float* __restrict__ item_table,
    const float* __restrict__ rate_table,
    const float* __restrict__ gv_W1, const float* __restrict__ gv_b1,
    const float* __restrict__ gv_W2, const float* __restrict__ gv_b2,
    const float* __restrict__ atti_W1, const float* __restrict__ atti_b1,
    const float* __restrict__ atti_W2, const float* __restrict__ atti_b2,
    const float* __restrict__ agg_W, const float* __restrict__ agg_b,
    float* __restrict__ out) {
  __shared__ __align__(16) float sW1[64 * 128];   // gv_W1 transposed+swizzled
  __shared__ __align__(16) float sW2[64 * 64];    // gv_W2
  __shared__ __align__(16) float sAW1[64 * 128];  // atti_W1
  __shared__ __align__(16) float sAW2[64];
  __shared__ float sB1[64], sB2[64], sAB1[64];
  __shared__ float sAB2s;
  __shared__ __align__(16) float sIn[40 * 128];   // chunk input rows
  __shared__ __align__(16) float sX[40 * 64];     // chunk x rows
  __shared__ __align__(16) float sH1[40 * 64];    // hidden scratch
  __shared__ __align__(16) float sU[64];          // group user emb
  __shared__ float sMask[40];
  __shared__ int sIID[40], sRID[40];
  __shared__ float sPart[8 * 64];
  __shared__ float sPartD[8];
  __shared__ float sC[64];

  const int tid = threadIdx.x;
  const int wave = tid >> 6;
  const int lane = tid & 63;
  const int swz = lane & 7;

  load_wt_swz<128>(sW1, gv_W1);
  load_wt_swz<64>(sW2, gv_W2);
  load_wt_swz<128>(sAW1, atti_W1);
  if (tid < 64) {
    sAW2[tid] = atti_W2[tid];
    sB1[tid] = gv_b1[tid];
    sB2[tid] = gv_b2[tid];
    sAB1[tid] = atti_b1[tid];
  }
  if (tid == 0) sAB2s = atti_b2[0];

  for (int g = 0; g < groups_per_block; ++g) {
    const int group = blockIdx.x * groups_per_block + g;
    __syncthreads();  // protect sU / per-group buffers from previous group
    if (tid < 64) sU[tid] = user_table[(size_t)uid_arr[group] * 64 + tid];
    float numer = 0.f;  // per-wave, lane j holds feature j
    float denom = 0.f;  // replicated across lanes

    for (int c0 = 0; c0 < n_items; c0 += 40) {
      const int csz = (n_items - c0 < 40) ? (n_items - c0) : 40;
      __syncthreads();  // previous chunk compute done; sU visible
      if (tid < csz) {
        const int2 pr = reinterpret_cast<const int2*>(ids)[(size_t)group * n_items + c0 + tid];
        sIID[tid] = pr.x;
        sRID[tid] = pr.y;
        sMask[tid] = pr.x > 0 ? 1.f : 0.f;
      }
      __syncthreads();
      for (int idx = tid; idx < (csz << 7); idx += 512) {
        const int r = idx >> 7;
        const int f = idx & 127;
        sIn[idx] = (f < 64) ? item_table[(size_t)sIID[r] * 64 + f]
                            : rate_table[sRID[r] * 64 + (f - 64)];
      }
      __syncthreads();

      // group-user contribution to attention layer-1 (row-independent):
      // uacc[j] = sum_k u[k] * atti_W1[64+k][j]
      float uacc = 0.f;
#pragma unroll
      for (int kb = 16; kb < 32; ++kb) {
        float4 w = reinterpret_cast<const float4*>(sAW1)[lane * 32 + (kb ^ swz)];
        float4 u = reinterpret_cast<const float4*>(sU)[kb - 16];
        uacc += dot4(w, u);
      }

      int rr[5];
      bool val[5];
#pragma unroll
      for (int i = 0; i < 5; ++i) {
        const int rl = wave + (i << 3);
        val[i] = rl < csz;
        rr[i] = val[i] ? rl : 0;
      }

      // ---- gv layer 1: 128 -> 64, relu ----
      float a1[5];
#pragma unroll
      for (int i = 0; i < 5; ++i) a1[i] = sB1[lane];
#pragma unroll
      for (int kb = 0; kb < 32; ++kb) {
        float4 w = reinterpret_cast<const float4*>(sW1)[lane * 32 + (kb ^ swz)];
#pragma unroll
        for (int i = 0; i < 5; ++i) {
          float4 x = reinterpret_cast<const float4*>(sIn)[rr[i] * 32 + kb];
          a1[i] += dot4(w, x);
        }
      }
#pragma unroll
      for (int i = 0; i < 5; ++i)
        if (val[i]) sH1[rr[i] * 64 + lane] = fmaxf(a1[i], 0.f);

      // ---- gv layer 2: 64 -> 64 (no relu) ----
      float a2[5];
#pragma unroll
      for (int i = 0; i < 5; ++i) a2[i] = sB2[lane];
#pragma unroll
      for (int kb = 0; kb < 16; ++kb) {
        float4 w = reinterpret_cast<const float4*>(sW2)[lane * 16 + (kb ^ swz)];
#pragma unroll
        for (int i = 0; i < 5; ++i) {
          float4 h = reinterpret_cast<const float4*>(sH1)[rr[i] * 16 + kb];
          a2[i] += dot4(w, h);
        }
      }
#pragma unroll
      for (int i = 0; i < 5; ++i)
        if (val[i]) sX[rr[i] * 64 + lane] = a2[i];

      // ---- attention layer 1 (x part) + factored u part, relu ----
      float a3[5];
#pragma unroll
      for (int i = 0; i < 5; ++i) a3[i] = sAB1[lane];
#pragma unroll
      for (int kb = 0; kb < 16; ++kb) {
        float4 w = reinterpret_cast<const float4*>(sAW1)[lane * 32 + (kb ^ swz)];
#pragma unroll
        for (int i = 0; i < 5; ++i) {
          float4 x = reinterpret_cast<const float4*>(sX)[rr[i] * 16 + kb];
          a3[i] += dot4(w, x);
        }
      }

      // ---- attention layer 2 (dot) + exp, accumulate numer/denom ----
#pragma unroll
      for (int i = 0; i < 5; ++i) {
        const float m = sMask[rr[i]];
        const float h = fmaxf(a3[i] + m * uacc, 0.f);
        const float tsum = wave_sum(h * sAW2[lane]);
        if (val[i]) {  // wave-uniform branch
          const float e = expf(tsum + sAB2s) * m;
          denom += e;
          numer = fmaf(e, sX[rr[i] * 64 + lane], numer);
        }
      }
    }

    // ---- cross-wave reduce + agg matvec + store ----
    sPart[(wave << 6) + lane] = numer;
    if (lane == 0) sPartD[wave] = denom;
    __syncthreads();
    if (wave == 0) {
      float n = 0.f, d = 0.f;
#pragma unroll
      for (int w = 0; w < 8; ++w) {
        n += sPart[(w << 6) + lane];
        d += sPartD[w];
      }
      const float c = n / (d + EPSV);
      sC[lane] = c;
      float a = agg_b[lane];
#pragma unroll 8
      for (int k = 0; k < 64; ++k) a = fmaf(sC[k], agg_W[(k << 6) + lane], a);
      out[(size_t)group * 64 + lane] = fmaxf(a, 0.f);
    }
  }
}

// ---------------------------------------------------------------------------
// Kernel 2: beta attention over neighbours + h_iS + final 3-layer MLP.
// One block per batch element b. 256 threads (4 waves), 10 rows (q) per wave.
// ---------------------------------------------------------------------------
__global__ __launch_bounds__(256) void stage2_kernel(
    const int* __restrict__ u_user_pad, const float* __restrict__ user_table,
    const float* __restrict__ hoI, const float* __restrict__ hiI,
    const float* __restrict__ attu_W1, const float* __restrict__ attu_b1,
    const float* __restrict__ attu_W2, const float* __restrict__ attu_b2,
    const float* __restrict__ aggn_W, const float* __restrict__ aggn_b,
    const float* __restrict__ cm_W1, const float* __restrict__ cm_b1,
    const float* __restrict__ cm_W2, const float* __restrict__ cm_b2,
    const float* __restrict__ cm_W3, const float* __restrict__ cm_b3,
    float* __restrict__ out) {
  __shared__ __align__(16) float sW1[64 * 128];  // attu_W1 transposed+swizzled
  __shared__ float sW2v[64], sB1[64];
  __shared__ float sB2s;
  __shared__ __align__(16) float sH[40 * 64];  // h_oI rows
  __shared__ __align__(16) float sN[40 * 64];  // neighbour embs
  __shared__ float sMask[40];
  __shared__ float sPart[4 * 64];
  __shared__ float sPartD[4];
  __shared__ float sF[128], sG[64];

  const int b = blockIdx.x;
  const int tid = threadIdx.x;
  const int wave = tid >> 6;
  const int lane = tid & 63;
  const int swz = lane & 7;

  load_wt_swz<128>(sW1, attu_W1);
  if (tid < 64) {
    sW2v[tid] = attu_W2[tid];
    sB1[tid] = attu_b1[tid];
  }
  if (tid == 0) sB2s = attu_b2[0];
  for (int idx = tid; idx < 40 * 64; idx += 256) sH[idx] = hoI[(size_t)b * 40 * 64 + idx];
  for (int idx = tid; idx < 40 * 64; idx += 256) {
    const int q = idx >> 6, f = idx & 63;
    const int uid = u_user_pad[b * 40 + q];
    sN[idx] = user_table[(size_t)uid * 64 + f];
  }
  if (tid < 40) sMask[tid] = u_user_pad[b * 40 + tid] > 0 ? 1.f : 0.f;
  __syncthreads();

  float numer = 0.f, denom = 0.f;
#pragma unroll
  for (int i = 0; i < 10; ++i) {
    const int q = wave + (i << 2);  // 4 waves x 10 = 40 rows
    float acc = sB1[lane];
#pragma unroll
    for (int kb = 0; kb < 16; ++kb) {
      float4 w = reinterpret_cast<const float4*>(sW1)[lane * 32 + (kb ^ swz)];
      float4 x = reinterpret_cast<const float4*>(sH)[q * 16 + kb];
      acc += dot4(w, x);
    }
#pragma unroll
    for (int kb = 16; kb < 32; ++kb) {
      float4 w = reinterpret_cast<const float4*>(sW1)[lane * 32 + (kb ^ swz)];
      float4 x = reinterpret_cast<const float4*>(sN)[q * 16 + (kb - 16)];
      acc += dot4(w, x);
    }
    const float tsum = wave_sum(fmaxf(acc, 0.f) * sW2v[lane]);
    const float e = expf(tsum + sB2s) * sMask[q];
    denom += e;
    numer = fmaf(e, sH[q * 64 + lane], numer);
  }

  sPart[(wave << 6) + lane] = numer;
  if (lane == 0) sPartD[wave] = denom;
  __syncthreads();
  if (wave == 0) {
    float n = 0.f, d = 0.f;
#pragma unroll
    for (int w = 0; w < 4; ++w) {
      n += sPart[(w << 6) + lane];
      d += sPartD[w];
    }
    const float hag = n / (d + EPSV);
    sG[lane] = hag;
    float a = aggn_b[lane];
#pragma unroll 8
    for (int k = 0; k < 64; ++k) a = fmaf(sG[k], aggn_W[(k << 6) + lane], a);
    const float hiS = fmaxf(a, 0.f);
    sF[lane] = hiI[(size_t)b * 64 + lane];
    sF[64 + lane] = hiS;
    float c1 = cm_b1[lane];
#pragma unroll 8
    for (int k = 0; k < 128; ++k) c1 = fmaf(sF[k], cm_W1[(k << 6) + lane], c1);
    sG[lane] = fmaxf(c1, 0.f);
    float c2 = cm_b2[lane];
#pragma unroll 8
    for (int k = 0; k < 64; ++k) c2 = fmaf(sG[k], cm_W2[(k << 6) + lane], c2);
    sF[lane] = fmaxf(c2, 0.f);
    float c3 = cm_b3[lane];
#pragma unroll 8
    for (int k = 0; k < 64; ++k) c3 = fmaf(sF[k], cm_W3[(k << 6) + lane], c3);
    out[(size_t)b * 64 + lane] = fmaxf(c3, 0.f);
  }
}

extern "C" void kernel_launch(void* const* d_in, const int* in_sizes, int n_in,
                              void* d_out, int out_size, void* d_ws, size_t ws_size,
                              hipStream_t stream) {
  const int* uids = (const int*)d_in[0];
  const int* u_item_pad = (const int*)d_in[1];
  const int* u_user_pad = (const int*)d_in[2];
  const int* u_user_item_pad = (const int*)d_in[3];
  const float* user_table = (const float*)d_in[4];
  const float* item_table = (const float*)d_in[5];
  const float* rate_table = (const float*)d_in[6];
  const float* gv_W1 = (const float*)d_in[7];
  const float* gv_b1 = (const float*)d_in[8];
  const float* gv_W2 = (const float*)d_in[9];
  const float* gv_b2 = (const float*)d_in[10];
  const float* atti_W1 = (const float*)d_in[11];
  const float* atti_b1 = (const float*)d_in[12];
  const float* atti_W2 = (const float*)d_in[13];
  const float* atti_b2 = (const float*)d_in[14];
  const float* agg_W = (const float*)d_in[15];
  const float* agg_b = (const float*)d_in[16];
  const float* attu_W1 = (const float*)d_in[17];
  const float* attu_b1 = (const float*)d_in[18];
  const float* attu_W2 = (const float*)d_in[19];
  const float* attu_b2 = (const float*)d_in[20];
  const float* aggn_W = (const float*)d_in[21];
  const float* aggn_b = (const float*)d_in[22];
  const float* cm_W1 = (const float*)d_in[23];
  const float* cm_b1 = (const float*)d_in[24];
  const float* cm_W2 = (const float*)d_in[25];
  const float* cm_b2 = (const float*)d_in[26];
  const float* cm_W3 = (const float*)d_in[27];
  const float* cm_b3 = (const float*)d_in[28];
  float* out = (float*)d_out;

  float* hoI = (float*)d_ws;            // 512*40*64 floats
  float* hiI = hoI + (size_t)512 * 40 * 64;  // 512*64 floats

  // S-branch: 512 blocks, each handles 40 (b,q) groups of 40 items.
  agg_kernel<<<512, 512, 0, stream>>>(40, 40, u_user_item_pad, u_user_pad,
                                      user_table, item_table, rate_table,
                                      gv_W1, gv_b1, gv_W2, gv_b2,
                                      atti_W1, atti_b1, atti_W2, atti_b2,
                                      agg_W, agg_b, hoI);
  // I-branch: 512 blocks, each handles 1 group of 100 items.
  agg_kernel<<<512, 512, 0, stream>>>(1, 100, u_item_pad, uids,
                                      user_table, item_table, rate_table,
                                      gv_W1, gv_b1, gv_W2, gv_b2,
                                      atti_W1, atti_b1, atti_W2, atti_b2,
                                      agg_W, agg_b, hiI);
  // Beta attention + h_iS + final MLP.
  stage2_kernel<<<512, 256, 0, stream>>>(u_user_pad, user_table, hoI, hiI,
                                         attu_W1, attu_b1, attu_W2, attu_b2,
                                         aggn_W, aggn_b,
                                         cm_W1, cm_b1, cm_W2, cm_b2, cm_W3, cm_b3,
                                         out);
}

// Round 2
// 1539.582 us; speedup vs baseline: 12.3010x; 12.3010x over previous
//
#include <hip/hip_runtime.h>
#include <math.h>

#define EPSV 1e-10f

// ---------------------------------------------------------------------------
// Weight staging: W is (K x 64) row-major in global. We store it transposed
// into LDS as Wt[j][K] (j = output feature = lane), with the float4 blocks of
// each row XOR-swizzled (block kb lands at kb ^ (j&7)) so that a wave reading
// lane-j's block kb hits all 32 banks at the optimal 8 dwords/bank.
// ---------------------------------------------------------------------------
template <int K>
__device__ __forceinline__ void load_wt_swz(float* dst, const float* __restrict__ W) {
  constexpr int NB = K / 4;
  for (int idx = threadIdx.x; idx < 64 * NB; idx += blockDim.x) {
    const int j = idx / NB;
    const int kb = idx % NB;
    float4 v;
    v.x = W[(4 * kb + 0) * 64 + j];
    v.y = W[(4 * kb + 1) * 64 + j];
    v.z = W[(4 * kb + 2) * 64 + j];
    v.w = W[(4 * kb + 3) * 64 + j];
    reinterpret_cast<float4*>(dst)[j * NB + (kb ^ (j & 7))] = v;
  }
}

__device__ __forceinline__ float dot4(float4 a, float4 b) {
  return a.x * b.x + a.y * b.y + a.z * b.z + a.w * b.w;
}

__device__ __forceinline__ float wave_sum(float t) {
#pragma unroll
  for (int off = 32; off > 0; off >>= 1) t += __shfl_xor(t, off, 64);
  return t;
}

// ---------------------------------------------------------------------------
// Kernel 1: fused item-aggregation (both I-branch and S-branch).
// One block = groups_per_block consecutive groups. Block = 512 threads.
// Rows processed in chunks of <=40; each wave owns rows wave+8i (i<5),
// interleaved so one weight ds_read_b128 feeds 5 rows (20 FMAs).
// __launch_bounds__(512,2): 8-wave block = 2 waves/SIMD -> full 256-VGPR
// budget; LDS (127KB) already limits to 1 block/CU, so no occupancy cost.
// ---------------------------------------------------------------------------
__global__ __launch_bounds__(512, 2) void agg_kernel(
    const int groups_per_block, const int n_items,
    const int* __restrict__ ids,      // [group][item][2] (item_id, rate_id)
    const int* __restrict__ uid_arr,  // [group] -> user id
    const float* __restrict__ user_table, const float* __restrict__ item_table,
    const float* __restrict__ rate_table,
    const float* __restrict__ gv_W1, const float* __restrict__ gv_b1,
    const float* __restrict__ gv_W2, const float* __restrict__ gv_b2,
    const float* __restrict__ atti_W1, const float* __restrict__ atti_b1,
    const float* __restrict__ atti_W2, const float* __restrict__ atti_b2,
    const float* __restrict__ agg_W, const float* __restrict__ agg_b,
    float* __restrict__ out) {
  __shared__ __align__(16) float sW1[64 * 128];   // gv_W1 transposed+swizzled
  __shared__ __align__(16) float sW2[64 * 64];    // gv_W2
  __shared__ __align__(16) float sAW1[64 * 128];  // atti_W1
  __shared__ __align__(16) float sAW2[64];
  __shared__ float sB1[64], sB2[64], sAB1[64];
  __shared__ float sAB2s;
  __shared__ __align__(16) float sIn[40 * 128];   // chunk input rows
  __shared__ __align__(16) float sX[40 * 64];     // chunk x rows
  __shared__ __align__(16) float sH1[40 * 64];    // hidden scratch
  __shared__ __align__(16) float sU[64];          // group user emb
  __shared__ float sMask[40];
  __shared__ int sIID[40], sRID[40];
  __shared__ float sPart[8 * 64];
  __shared__ float sPartD[8];
  __shared__ float sC[64];

  const int tid = threadIdx.x;
  const int wave = tid >> 6;
  const int lane = tid & 63;
  const int swz = lane & 7;

  load_wt_swz<128>(sW1, gv_W1);
  load_wt_swz<64>(sW2, gv_W2);
  load_wt_swz<128>(sAW1, atti_W1);
  if (tid < 64) {
    sAW2[tid] = atti_W2[tid];
    sB1[tid] = gv_b1[tid];
    sB2[tid] = gv_b2[tid];
    sAB1[tid] = atti_b1[tid];
  }
  if (tid == 0) sAB2s = atti_b2[0];

  for (int g = 0; g < groups_per_block; ++g) {
    const int group = blockIdx.x * groups_per_block + g;
    __syncthreads();  // protect per-group buffers from previous group
    if (tid < 64) sU[tid] = user_table[(size_t)uid_arr[group] * 64 + tid];
    float numer = 0.f;  // per-wave, lane j holds feature j
    float denom = 0.f;  // replicated across lanes

    for (int c0 = 0; c0 < n_items; c0 += 40) {
      const int csz = (n_items - c0 < 40) ? (n_items - c0) : 40;
      __syncthreads();  // previous chunk compute done
      if (tid < csz) {
        const int2 pr = reinterpret_cast<const int2*>(ids)[(size_t)group * n_items + c0 + tid];
        sIID[tid] = pr.x;
        sRID[tid] = pr.y;
        sMask[tid] = pr.x > 0 ? 1.f : 0.f;
      }
      __syncthreads();
      // float4-vectorized gather staging: [row r][float4 block fb]
      for (int idx = tid; idx < (csz << 5); idx += 512) {
        const int r = idx >> 5;
        const int fb = idx & 31;
        float4 v;
        if (fb < 16)
          v = reinterpret_cast<const float4*>(item_table)[(size_t)sIID[r] * 16 + fb];
        else
          v = reinterpret_cast<const float4*>(rate_table)[sRID[r] * 16 + (fb - 16)];
        reinterpret_cast<float4*>(sIn)[idx] = v;
      }
      __syncthreads();

      // group-user contribution to attention layer-1 (row-independent):
      float uacc = 0.f;
#pragma unroll 8
      for (int kb = 16; kb < 32; ++kb) {
        float4 w = reinterpret_cast<const float4*>(sAW1)[lane * 32 + (kb ^ swz)];
        float4 u = reinterpret_cast<const float4*>(sU)[kb - 16];
        uacc += dot4(w, u);
      }

      int rr[5];
      bool val[5];
#pragma unroll
      for (int i = 0; i < 5; ++i) {
        const int rl = wave + (i << 3);
        val[i] = rl < csz;
        rr[i] = val[i] ? rl : 0;
      }

      // ---- gv layer 1: 128 -> 64, relu ----
      float a1[5];
#pragma unroll
      for (int i = 0; i < 5; ++i) a1[i] = sB1[lane];
#pragma unroll 8
      for (int kb = 0; kb < 32; ++kb) {
        float4 w = reinterpret_cast<const float4*>(sW1)[lane * 32 + (kb ^ swz)];
#pragma unroll
        for (int i = 0; i < 5; ++i) {
          float4 x = reinterpret_cast<const float4*>(sIn)[rr[i] * 32 + kb];
          a1[i] += dot4(w, x);
        }
      }
#pragma unroll
      for (int i = 0; i < 5; ++i)
        if (val[i]) sH1[rr[i] * 64 + lane] = fmaxf(a1[i], 0.f);

      // ---- gv layer 2: 64 -> 64 (no relu) ----
      float a2[5];
#pragma unroll
      for (int i = 0; i < 5; ++i) a2[i] = sB2[lane];
#pragma unroll 8
      for (int kb = 0; kb < 16; ++kb) {
        float4 w = reinterpret_cast<const float4*>(sW2)[lane * 16 + (kb ^ swz)];
#pragma unroll
        for (int i = 0; i < 5; ++i) {
          float4 h = reinterpret_cast<const float4*>(sH1)[rr[i] * 16 + kb];
          a2[i] += dot4(w, h);
        }
      }
#pragma unroll
      for (int i = 0; i < 5; ++i)
        if (val[i]) sX[rr[i] * 64 + lane] = a2[i];

      // ---- attention layer 1 (x part) + factored u part, relu ----
      float a3[5];
#pragma unroll
      for (int i = 0; i < 5; ++i) a3[i] = sAB1[lane];
#pragma unroll 8
      for (int kb = 0; kb < 16; ++kb) {
        float4 w = reinterpret_cast<const float4*>(sAW1)[lane * 32 + (kb ^ swz)];
#pragma unroll
        for (int i = 0; i < 5; ++i) {
          float4 x = reinterpret_cast<const float4*>(sX)[rr[i] * 16 + kb];
          a3[i] += dot4(w, x);
        }
      }

      // ---- attention layer 2 (dot) + exp, accumulate numer/denom ----
#pragma unroll
      for (int i = 0; i < 5; ++i) {
        const float m = sMask[rr[i]];
        const float h = fmaxf(a3[i] + m * uacc, 0.f);
        const float tsum = wave_sum(h * sAW2[lane]);
        if (val[i]) {  // wave-uniform branch
          const float e = __expf(tsum + sAB2s) * m;
          denom += e;
          numer = fmaf(e, sX[rr[i] * 64 + lane], numer);
        }
      }
    }

    // ---- cross-wave reduce + agg matvec + store ----
    sPart[(wave << 6) + lane] = numer;
    if (lane == 0) sPartD[wave] = denom;
    __syncthreads();
    if (wave == 0) {
      float n = 0.f, d = 0.f;
#pragma unroll
      for (int w = 0; w < 8; ++w) {
        n += sPart[(w << 6) + lane];
        d += sPartD[w];
      }
      const float c = n / (d + EPSV);
      sC[lane] = c;
      float a = agg_b[lane];
#pragma unroll 8
      for (int k = 0; k < 64; ++k) a = fmaf(sC[k], agg_W[(k << 6) + lane], a);
      out[(size_t)group * 64 + lane] = fmaxf(a, 0.f);
    }
  }
}

// ---------------------------------------------------------------------------
// Kernel 2: beta attention over neighbours + h_iS + final 3-layer MLP.
// One block per batch element b. 256 threads (4 waves), 10 rows (q) per wave.
// ---------------------------------------------------------------------------
__global__ __launch_bounds__(256, 1) void stage2_kernel(
    const int* __restrict__ u_user_pad, const float* __restrict__ user_table,
    const float* __restrict__ hoI, const float* __restrict__ hiI,
    const float* __restrict__ attu_W1, const float* __restrict__ attu_b1,
    const float* __restrict__ attu_W2, const float* __restrict__ attu_b2,
    const float* __restrict__ aggn_W, const float* __restrict__ aggn_b,
    const float* __restrict__ cm_W1, const float* __restrict__ cm_b1,
    const float* __restrict__ cm_W2, const float* __restrict__ cm_b2,
    const float* __restrict__ cm_W3, const float* __restrict__ cm_b3,
    float* __restrict__ out) {
  __shared__ __align__(16) float sW1[64 * 128];  // attu_W1 transposed+swizzled
  __shared__ float sW2v[64], sB1[64];
  __shared__ float sB2s;
  __shared__ __align__(16) float sH[40 * 64];  // h_oI rows
  __shared__ __align__(16) float sN[40 * 64];  // neighbour embs
  __shared__ float sMask[40];
  __shared__ float sPart[4 * 64];
  __shared__ float sPartD[4];
  __shared__ float sF[128], sG[64];

  const int b = blockIdx.x;
  const int tid = threadIdx.x;
  const int wave = tid >> 6;
  const int lane = tid & 63;
  const int swz = lane & 7;

  load_wt_swz<128>(sW1, attu_W1);
  if (tid < 64) {
    sW2v[tid] = attu_W2[tid];
    sB1[tid] = attu_b1[tid];
  }
  if (tid == 0) sB2s = attu_b2[0];
  for (int idx = tid; idx < 40 * 16; idx += 256)
    reinterpret_cast<float4*>(sH)[idx] =
        reinterpret_cast<const float4*>(hoI)[(size_t)b * 40 * 16 + idx];
  for (int idx = tid; idx < 40 * 16; idx += 256) {
    const int q = idx >> 4, fb = idx & 15;
    const int uid = u_user_pad[b * 40 + q];
    reinterpret_cast<float4*>(sN)[idx] =
        reinterpret_cast<const float4*>(user_table)[(size_t)uid * 16 + fb];
  }
  if (tid < 40) sMask[tid] = u_user_pad[b * 40 + tid] > 0 ? 1.f : 0.f;
  __syncthreads();

  float numer = 0.f, denom = 0.f;
#pragma unroll
  for (int i = 0; i < 10; ++i) {
    const int q = wave + (i << 2);  // 4 waves x 10 = 40 rows
    float acc = sB1[lane];
#pragma unroll 8
    for (int kb = 0; kb < 16; ++kb) {
      float4 w = reinterpret_cast<const float4*>(sW1)[lane * 32 + (kb ^ swz)];
      float4 x = reinterpret_cast<const float4*>(sH)[q * 16 + kb];
      acc += dot4(w, x);
    }
#pragma unroll 8
    for (int kb = 16; kb < 32; ++kb) {
      float4 w = reinterpret_cast<const float4*>(sW1)[lane * 32 + (kb ^ swz)];
      float4 x = reinterpret_cast<const float4*>(sN)[q * 16 + (kb - 16)];
      acc += dot4(w, x);
    }
    const float tsum = wave_sum(fmaxf(acc, 0.f) * sW2v[lane]);
    const float e = __expf(tsum + sB2s) * sMask[q];
    denom += e;
    numer = fmaf(e, sH[q * 64 + lane], numer);
  }

  sPart[(wave << 6) + lane] = numer;
  if (lane == 0) sPartD[wave] = denom;
  __syncthreads();
  if (wave == 0) {
    float n = 0.f, d = 0.f;
#pragma unroll
    for (int w = 0; w < 4; ++w) {
      n += sPart[(w << 6) + lane];
      d += sPartD[w];
    }
    const float hag = n / (d + EPSV);
    sG[lane] = hag;
    float a = aggn_b[lane];
#pragma unroll 8
    for (int k = 0; k < 64; ++k) a = fmaf(sG[k], aggn_W[(k << 6) + lane], a);
    const float hiS = fmaxf(a, 0.f);
    sF[lane] = hiI[(size_t)b * 64 + lane];
    sF[64 + lane] = hiS;
    float c1 = cm_b1[lane];
#pragma unroll 8
    for (int k = 0; k < 128; ++k) c1 = fmaf(sF[k], cm_W1[(k << 6) + lane], c1);
    sG[lane] = fmaxf(c1, 0.f);
    float c2 = cm_b2[lane];
#pragma unroll 8
    for (int k = 0; k < 64; ++k) c2 = fmaf(sG[k], cm_W2[(k << 6) + lane], c2);
    sF[lane] = fmaxf(c2, 0.f);
    float c3 = cm_b3[lane];
#pragma unroll 8
    for (int k = 0; k < 64; ++k) c3 = fmaf(sF[k], cm_W3[(k << 6) + lane], c3);
    out[(size_t)b * 64 + lane] = fmaxf(c3, 0.f);
  }
}

extern "C" void kernel_launch(void* const* d_in, const int* in_sizes, int n_in,
                              void* d_out, int out_size, void* d_ws, size_t ws_size,
                              hipStream_t stream) {
  const int* uids = (const int*)d_in[0];
  const int* u_item_pad = (const int*)d_in[1];
  const int* u_user_pad = (const int*)d_in[2];
  const int* u_user_item_pad = (const int*)d_in[3];
  const float* user_table = (const float*)d_in[4];
  const float* item_table = (const float*)d_in[5];
  const float* rate_table = (const float*)d_in[6];
  const float* gv_W1 = (const float*)d_in[7];
  const float* gv_b1 = (const float*)d_in[8];
  const float* gv_W2 = (const float*)d_in[9];
  const float* gv_b2 = (const float*)d_in[10];
  const float* atti_W1 = (const float*)d_in[11];
  const float* atti_b1 = (const float*)d_in[12];
  const float* atti_W2 = (const float*)d_in[13];
  const float* atti_b2 = (const float*)d_in[14];
  const float* agg_W = (const float*)d_in[15];
  const float* agg_b = (const float*)d_in[16];
  const float* attu_W1 = (const float*)d_in[17];
  const float* attu_b1 = (const float*)d_in[18];
  const float* attu_W2 = (const float*)d_in[19];
  const float* attu_b2 = (const float*)d_in[20];
  const float* aggn_W = (const float*)d_in[21];
  const float* aggn_b = (const float*)d_in[22];
  const float* cm_W1 = (const float*)d_in[23];
  const float* cm_b1 = (const float*)d_in[24];
  const float* cm_W2 = (const float*)d_in[25];
  const float* cm_b2 = (const float*)d_in[26];
  const float* cm_W3 = (const float*)d_in[27];
  const float* cm_b3 = (const float*)d_in[28];
  float* out = (float*)d_out;

  float* hoI = (float*)d_ws;                 // 512*40*64 floats
  float* hiI = hoI + (size_t)512 * 40 * 64;  // 512*64 floats

  // S-branch: 512 blocks, each handles 40 (b,q) groups of 40 items.
  agg_kernel<<<512, 512, 0, stream>>>(40, 40, u_user_item_pad, u_user_pad,
                                      user_table, item_table, rate_table,
                                      gv_W1, gv_b1, gv_W2, gv_b2,
                                      atti_W1, atti_b1, atti_W2, atti_b2,
                                      agg_W, agg_b, hoI);
  // I-branch: 512 blocks, each handles 1 group of 100 items.
  agg_kernel<<<512, 512, 0, stream>>>(1, 100, u_item_pad, uids,
                                      user_table, item_table, rate_table,
                                      gv_W1, gv_b1, gv_W2, gv_b2,
                                      atti_W1, atti_b1, atti_W2, atti_b2,
                                      agg_W, agg_b, hiI);
  // Beta attention + h_iS + final MLP.
  stage2_kernel<<<512, 256, 0, stream>>>(u_user_pad, user_table, hoI, hiI,
                                         attu_W1, attu_b1, attu_W2, attu_b2,
                                         aggn_W, aggn_b,
                                         cm_W1, cm_b1, cm_W2, cm_b2, cm_W3, cm_b3,
                                         out);
}

// Round 3
// 481.115 us; speedup vs baseline: 39.3636x; 3.2000x over previous
//
#include <hip/hip_runtime.h>
#include <math.h>

#define EPSV 1e-10f
#define CH 96

typedef _Float16 f16x8 __attribute__((ext_vector_type(8)));
typedef float f32x4 __attribute__((ext_vector_type(4)));

// ---------------- LDS layout (bytes) ----------------
#define OFF_W1T   0        // 16384 f16 W1t[n][k] swz   (phase0: AW1ut f32 64x64)
#define OFF_W2T   16384    // 8192  f16 W2t
#define OFF_AW1X  24576    // 8192  f16 AW1x t
#define OFF_X     32768    // 24576 = 96 rows * 256B f16 (phase0: uS f32 NG*64)
#define OFF_V     57344    // 10240 = 40*64 f32
#define OFF_NUM   67584    // 512   2*64 f32
#define OFF_DEN   68096    // 16
#define OFF_MASK  68112    // 384
#define OFF_IID   68496    // 384
#define OFF_RID   68880    // 384
#define OFF_B1    69264    // 256
#define OFF_B2    69520    // 256
#define OFF_AB1   69776    // 256
#define OFF_AW2   70032    // 256
#define OFF_AB2   70288    // 16
#define SMEM_SZ   70304

// ---------------------------------------------------------------------------
// Fused item-aggregation with f16 MFMA (16x16x32), f32 accumulation.
// Groups padded to G rows; chunk = 96 rows = 6 M-tiles; wave w owns tile w.
// X region per row: 256B = 16 swizzled 16B blocks; cols 0..127 = input,
// layer1 overwrites cols 0..63 (H), layer2 writes cols 64..127 (x_ia f16).
// Swizzle: 16B block bb of row r stored at bb ^ (r&7)  (2-way max conflict).
// ---------------------------------------------------------------------------
__global__ __launch_bounds__(384, 3) void agg_kernel(
    const int NG, const int P, const int G,
    const int* __restrict__ ids, const int* __restrict__ uid_arr,
    const float* __restrict__ user_table, const float* __restrict__ item_table,
    const float* __restrict__ rate_table,
    const float* __restrict__ gv_W1, const float* __restrict__ gv_b1,
    const float* __restrict__ gv_W2, const float* __restrict__ gv_b2,
    const float* __restrict__ atti_W1, const float* __restrict__ atti_b1,
    const float* __restrict__ atti_W2, const float* __restrict__ atti_b2,
    const float* __restrict__ agg_W, const float* __restrict__ agg_b,
    float* __restrict__ out) {
  __shared__ __align__(16) char smem[SMEM_SZ];
  const int tid = threadIdx.x;
  const int wave = tid >> 6, lane = tid & 63;
  const int quad = lane >> 4, mrow = lane & 15;

  float* sV = (float*)(smem + OFF_V);
  float* sNum = (float*)(smem + OFF_NUM);
  float* sDen = (float*)(smem + OFF_DEN);
  float* sMask = (float*)(smem + OFF_MASK);
  int* sIID = (int*)(smem + OFF_IID);
  int* sRID = (int*)(smem + OFF_RID);
  char* smX = smem + OFF_X;

  // ---- phase0: stage u embeddings (X region) + AW1u^T f32 (W1T region) ----
  {
    float* uS = (float*)smX;
    float* AU = (float*)(smem + OFF_W1T);
    for (int t = tid; t < NG * 64; t += 384) {
      const int g = t >> 6, f = t & 63;
      uS[t] = user_table[(size_t)uid_arr[blockIdx.x * NG + g] * 64 + f];
    }
    for (int t = tid; t < 4096; t += 384) {
      const int j = t >> 6, k = t & 63;
      // swizzled: float4 block (k>>2) of row j stored at (k>>2)^(j&15)
      AU[j * 64 + ((((k >> 2) ^ (j & 15))) << 2) + (k & 3)] =
          atti_W1[(64 + k) * 64 + j];
    }
    for (int t = tid; t < 2560; t += 384) sV[t] = 0.f;
    if (tid < 128) sNum[tid] = 0.f;
    if (tid < 2) sDen[tid] = 0.f;
  }
  __syncthreads();
  // ---- phase1: v[g][j] = u[g] . AW1u[:,j] ----
  {
    const float4* u4 = (const float4*)smX;
    const float4* a4 = (const float4*)(smem + OFF_W1T);
    for (int t = tid; t < NG * 64; t += 384) {
      const int g = t >> 6, j = t & 63;
      float s = 0.f;
#pragma unroll 4
      for (int kb = 0; kb < 16; ++kb) {
        const float4 uu = u4[g * 16 + kb];
        const float4 aa = a4[j * 16 + (kb ^ (j & 15))];
        s += uu.x * aa.x + uu.y * aa.y + uu.z * aa.z + uu.w * aa.w;
      }
      sV[t] = s;
    }
  }
  __syncthreads();
  // ---- phase2: f16 weight staging (B-operand layout Wt[n][k], swizzled) ----
  for (int t = tid; t < 1024; t += 384) {  // gv_W1 (128x64)
    const int n = t >> 4, kb = t & 15;
    f16x8 h;
#pragma unroll
    for (int j = 0; j < 8; ++j) h[j] = (_Float16)gv_W1[(kb * 8 + j) * 64 + n];
    *(f16x8*)(smem + OFF_W1T + n * 256 + ((kb ^ (n & 7)) << 4)) = h;
  }
  for (int t = tid; t < 512; t += 384) {  // gv_W2 (64x64)
    const int n = t >> 3, kb = t & 7;
    f16x8 h;
#pragma unroll
    for (int j = 0; j < 8; ++j) h[j] = (_Float16)gv_W2[(kb * 8 + j) * 64 + n];
    *(f16x8*)(smem + OFF_W2T + n * 128 + ((kb ^ (n & 7)) << 4)) = h;
  }
  for (int t = tid; t < 512; t += 384) {  // atti_W1 rows 0..63
    const int n = t >> 3, kb = t & 7;
    f16x8 h;
#pragma unroll
    for (int j = 0; j < 8; ++j) h[j] = (_Float16)atti_W1[(kb * 8 + j) * 64 + n];
    *(f16x8*)(smem + OFF_AW1X + n * 128 + ((kb ^ (n & 7)) << 4)) = h;
  }
  if (tid < 64) {
    ((float*)(smem + OFF_B1))[tid] = gv_b1[tid];
    ((float*)(smem + OFF_B2))[tid] = gv_b2[tid];
    ((float*)(smem + OFF_AB1))[tid] = atti_b1[tid];
    ((float*)(smem + OFF_AW2))[tid] = atti_W2[tid];
  }
  if (tid == 0) ((float*)(smem + OFF_AB2))[0] = atti_b2[0];

  const int totRows = NG * G;
  for (int c0 = 0; c0 < totRows; c0 += CH) {
    __syncthreads();  // B_a: prev compute/epilogue done (covers phase2 1st it)
    if (tid < CH) {
      const int gr = c0 + tid;
      const int g = gr / G, it = gr % G;
      int iid = 0, rid = 0;
      float m = 0.f;
      if (g < NG && it < P) {
        const int2 pr = ((const int2*)ids)[(size_t)(blockIdx.x * NG + g) * P + it];
        iid = pr.x; rid = pr.y;
        m = (pr.x > 0) ? 1.f : 0.f;
      }
      sIID[tid] = iid; sRID[tid] = rid; sMask[tid] = m;
    }
    __syncthreads();  // B_b
    for (int t = tid; t < CH * 16; t += 384) {
      const int r = t >> 4, bb = t & 15;
      const float* src = (bb < 8) ? (item_table + (size_t)sIID[r] * 64 + bb * 8)
                                  : (rate_table + (size_t)sRID[r] * 64 + (bb - 8) * 8);
      const float4 p = ((const float4*)src)[0];
      const float4 q = ((const float4*)src)[1];
      f16x8 h;
      h[0] = (_Float16)p.x; h[1] = (_Float16)p.y;
      h[2] = (_Float16)p.z; h[3] = (_Float16)p.w;
      h[4] = (_Float16)q.x; h[5] = (_Float16)q.y;
      h[6] = (_Float16)q.z; h[7] = (_Float16)q.w;
      *(f16x8*)(smX + r * 256 + ((bb ^ (r & 7)) << 4)) = h;
    }
    __syncthreads();  // B_c
    // ---------------- compute: wave = M-tile ----------------
    {
      const int r0 = wave * 16;
      const int arow = r0 + mrow;  // A-operand row this lane supplies
      const int sw = arow & 7;
      const int gb = (c0 + r0) / G;       // group (block-local index)
      const int gl = gb - c0 / G;         // numer/denom slot 0/1
      // layer1: A-frags (k = quad*8 + 32*ks)
      f16x8 a1[4];
#pragma unroll
      for (int ks = 0; ks < 4; ++ks)
        a1[ks] = *(const f16x8*)(smX + arow * 256 + (((quad + ks * 4) ^ sw) << 4));
      const float* sB1f = (const float*)(smem + OFF_B1);
#pragma unroll
      for (int nt = 0; nt < 4; ++nt) {
        f32x4 c = {0.f, 0.f, 0.f, 0.f};
        const int n = nt * 16 + mrow;
#pragma unroll
        for (int ks = 0; ks < 4; ++ks) {
          const f16x8 b = *(const f16x8*)(smem + OFF_W1T + n * 256 +
                                          (((quad + ks * 4) ^ (n & 7)) << 4));
          c = __builtin_amdgcn_mfma_f32_16x16x32_f16(a1[ks], b, c, 0, 0, 0);
        }
        const float bia = sB1f[n];
#pragma unroll
        for (int rg = 0; rg < 4; ++rg) {  // D: row = quad*4+rg, col = n
          const int rw = r0 + quad * 4 + rg;
          const float h = fmaxf(c[rg] + bia, 0.f);
          *(_Float16*)(smX + rw * 256 + (((n >> 3) ^ (rw & 7)) << 4) +
                       ((n & 7) << 1)) = (_Float16)h;
        }
      }
      // layer2: A from H (cols 0..63)
      f16x8 a2[2];
#pragma unroll
      for (int ks = 0; ks < 2; ++ks)
        a2[ks] = *(const f16x8*)(smX + arow * 256 + (((quad + ks * 4) ^ sw) << 4));
      const float* sB2f = (const float*)(smem + OFF_B2);
      f32x4 x2a[4];
#pragma unroll
      for (int nt = 0; nt < 4; ++nt) {
        f32x4 c = {0.f, 0.f, 0.f, 0.f};
        const int n = nt * 16 + mrow;
#pragma unroll
        for (int ks = 0; ks < 2; ++ks) {
          const f16x8 b = *(const f16x8*)(smem + OFF_W2T + n * 128 +
                                          (((quad + ks * 4) ^ (n & 7)) << 4));
          c = __builtin_amdgcn_mfma_f32_16x16x32_f16(a2[ks], b, c, 0, 0, 0);
        }
        const float bia = sB2f[n];
#pragma unroll
        for (int rg = 0; rg < 4; ++rg) c[rg] += bia;
        x2a[nt] = c;  // x_ia f32, rows quad*4+rg, col n
#pragma unroll
        for (int rg = 0; rg < 4; ++rg) {
          const int rw = r0 + quad * 4 + rg;
          const int cc = 64 + n;
          *(_Float16*)(smX + rw * 256 + (((cc >> 3) ^ (rw & 7)) << 4) +
                       ((cc & 7) << 1)) = (_Float16)c[rg];
        }
      }
      // att layer1: A from x_ia f16 (cols 64..127)
      f16x8 a3[2];
#pragma unroll
      for (int ks = 0; ks < 2; ++ks)
        a3[ks] = *(const f16x8*)(smX + arow * 256 +
                                 (((8 + quad + ks * 4) ^ sw) << 4));
      float mk[4];
#pragma unroll
      for (int rg = 0; rg < 4; ++rg) mk[rg] = sMask[r0 + quad * 4 + rg];
      const float* sAB1f = (const float*)(smem + OFF_AB1);
      const float* sAW2f = (const float*)(smem + OFF_AW2);
      float tl[4] = {0.f, 0.f, 0.f, 0.f};
#pragma unroll
      for (int nt = 0; nt < 4; ++nt) {
        f32x4 c = {0.f, 0.f, 0.f, 0.f};
        const int n = nt * 16 + mrow;
#pragma unroll
        for (int ks = 0; ks < 2; ++ks) {
          const f16x8 b = *(const f16x8*)(smem + OFF_AW1X + n * 128 +
                                          (((quad + ks * 4) ^ (n & 7)) << 4));
          c = __builtin_amdgcn_mfma_f32_16x16x32_f16(a3[ks], b, c, 0, 0, 0);
        }
        const float vb = sV[gb * 64 + n];
        const float b1a = sAB1f[n];
        const float w2 = sAW2f[n];
#pragma unroll
        for (int rg = 0; rg < 4; ++rg) {
          const float h = fmaxf(c[rg] + b1a + mk[rg] * vb, 0.f);
          tl[rg] = fmaf(h, w2, tl[rg]);
        }
      }
      const float ab2v = ((const float*)(smem + OFF_AB2))[0];
      float e[4], dsum = 0.f;
#pragma unroll
      for (int rg = 0; rg < 4; ++rg) {
        float t = tl[rg];  // reduce over the 16 cols held by this quad
        t += __shfl_xor(t, 1); t += __shfl_xor(t, 2);
        t += __shfl_xor(t, 4); t += __shfl_xor(t, 8);
        e[rg] = __expf(t + ab2v) * mk[rg];
        dsum += e[rg];
      }
      dsum += __shfl_xor(dsum, 16); dsum += __shfl_xor(dsum, 32);
      if (lane == 0) atomicAdd(sDen + gl, dsum);
#pragma unroll
      for (int nt = 0; nt < 4; ++nt) {
        float s = e[0] * x2a[nt][0] + e[1] * x2a[nt][1] +
                  e[2] * x2a[nt][2] + e[3] * x2a[nt][3];
        s += __shfl_xor(s, 16); s += __shfl_xor(s, 32);
        if (quad == 0) atomicAdd(sNum + gl * 64 + nt * 16 + mrow, s);
      }
    }
    __syncthreads();  // B_d
    // ---- epilogue for groups completed in this chunk ----
    if (wave < 2) {
      const int g = c0 / G + wave;
      if (g < NG && (g + 1) * G > c0 && (g + 1) * G <= c0 + CH) {
        const int gl = wave;
        const float rd = 1.f / (sDen[gl] + EPSV);
        float acc = 0.f;
#pragma unroll 8
        for (int k = 0; k < 64; ++k)
          acc = fmaf(sNum[gl * 64 + k], agg_W[k * 64 + lane], acc);
        out[(size_t)(blockIdx.x * NG + g) * 64 + lane] =
            fmaxf(acc * rd + agg_b[lane], 0.f);
        sNum[gl * 64 + lane] = 0.f;
        if (lane == 0) sDen[gl] = 0.f;
      }
    }
  }
}

// ---------------------------------------------------------------------------
// helpers for stage2 (unchanged VALU path)
// ---------------------------------------------------------------------------
template <int K>
__device__ __forceinline__ void load_wt_swz(float* dst, const float* __restrict__ W) {
  constexpr int NB = K / 4;
  for (int idx = threadIdx.x; idx < 64 * NB; idx += blockDim.x) {
    const int j = idx / NB;
    const int kb = idx % NB;
    float4 v;
    v.x = W[(4 * kb + 0) * 64 + j];
    v.y = W[(4 * kb + 1) * 64 + j];
    v.z = W[(4 * kb + 2) * 64 + j];
    v.w = W[(4 * kb + 3) * 64 + j];
    reinterpret_cast<float4*>(dst)[j * NB + (kb ^ (j & 7))] = v;
  }
}

__device__ __forceinline__ float dot4(float4 a, float4 b) {
  return a.x * b.x + a.y * b.y + a.z * b.z + a.w * b.w;
}

__device__ __forceinline__ float wave_sum(float t) {
#pragma unroll
  for (int off = 32; off > 0; off >>= 1) t += __shfl_xor(t, off, 64);
  return t;
}

// ---------------------------------------------------------------------------
// Kernel 2: beta attention over neighbours + h_iS + final 3-layer MLP.
// ---------------------------------------------------------------------------
__global__ __launch_bounds__(256, 1) void stage2_kernel(
    const int* __restrict__ u_user_pad, const float* __restrict__ user_table,
    const float* __restrict__ hoI, const float* __restrict__ hiI,
    const float* __restrict__ attu_W1, const float* __restrict__ attu_b1,
    const float* __restrict__ attu_W2, const float* __restrict__ attu_b2,
    const float* __restrict__ aggn_W, const float* __restrict__ aggn_b,
    const float* __restrict__ cm_W1, const float* __restrict__ cm_b1,
    const float* __restrict__ cm_W2, const float* __restrict__ cm_b2,
    const float* __restrict__ cm_W3, const float* __restrict__ cm_b3,
    float* __restrict__ out) {
  __shared__ __align__(16) float sW1[64 * 128];
  __shared__ float sW2v[64], sB1[64];
  __shared__ float sB2s;
  __shared__ __align__(16) float sH[40 * 64];
  __shared__ __align__(16) float sN[40 * 64];
  __shared__ float sMask[40];
  __shared__ float sPart[4 * 64];
  __shared__ float sPartD[4];
  __shared__ float sF[128], sG[64];

  const int b = blockIdx.x;
  const int tid = threadIdx.x;
  const int wave = tid >> 6;
  const int lane = tid & 63;
  const int swz = lane & 7;

  load_wt_swz<128>(sW1, attu_W1);
  if (tid < 64) {
    sW2v[tid] = attu_W2[tid];
    sB1[tid] = attu_b1[tid];
  }
  if (tid == 0) sB2s = attu_b2[0];
  for (int idx = tid; idx < 40 * 16; idx += 256)
    reinterpret_cast<float4*>(sH)[idx] =
        reinterpret_cast<const float4*>(hoI)[(size_t)b * 40 * 16 + idx];
  for (int idx = tid; idx < 40 * 16; idx += 256) {
    const int q = idx >> 4, fb = idx & 15;
    const int uid = u_user_pad[b * 40 + q];
    reinterpret_cast<float4*>(sN)[idx] =
        reinterpret_cast<const float4*>(user_table)[(size_t)uid * 16 + fb];
  }
  if (tid < 40) sMask[tid] = u_user_pad[b * 40 + tid] > 0 ? 1.f : 0.f;
  __syncthreads();

  float numer = 0.f, denom = 0.f;
#pragma unroll
  for (int i = 0; i < 10; ++i) {
    const int q = wave + (i << 2);
    float acc = sB1[lane];
#pragma unroll 8
    for (int kb = 0; kb < 16; ++kb) {
      float4 w = reinterpret_cast<const float4*>(sW1)[lane * 32 + (kb ^ swz)];
      float4 x = reinterpret_cast<const float4*>(sH)[q * 16 + kb];
      acc += dot4(w, x);
    }
#pragma unroll 8
    for (int kb = 16; kb < 32; ++kb) {
      float4 w = reinterpret_cast<const float4*>(sW1)[lane * 32 + (kb ^ swz)];
      float4 x = reinterpret_cast<const float4*>(sN)[q * 16 + (kb - 16)];
      acc += dot4(w, x);
    }
    const float tsum = wave_sum(fmaxf(acc, 0.f) * sW2v[lane]);
    const float e = __expf(tsum + sB2s) * sMask[q];
    denom += e;
    numer = fmaf(e, sH[q * 64 + lane], numer);
  }

  sPart[(wave << 6) + lane] = numer;
  if (lane == 0) sPartD[wave] = denom;
  __syncthreads();
  if (wave == 0) {
    float n = 0.f, d = 0.f;
#pragma unroll
    for (int w = 0; w < 4; ++w) {
      n += sPart[(w << 6) + lane];
      d += sPartD[w];
    }
    const float hag = n / (d + EPSV);
    sG[lane] = hag;
    float a = aggn_b[lane];
#pragma unroll 8
    for (int k = 0; k < 64; ++k) a = fmaf(sG[k], aggn_W[(k << 6) + lane], a);
    const float hiS = fmaxf(a, 0.f);
    sF[lane] = hiI[(size_t)b * 64 + lane];
    sF[64 + lane] = hiS;
    float c1 = cm_b1[lane];
#pragma unroll 8
    for (int k = 0; k < 128; ++k) c1 = fmaf(sF[k], cm_W1[(k << 6) + lane], c1);
    sG[lane] = fmaxf(c1, 0.f);
    float c2 = cm_b2[lane];
#pragma unroll 8
    for (int k = 0; k < 64; ++k) c2 = fmaf(sG[k], cm_W2[(k << 6) + lane], c2);
    sF[lane] = fmaxf(c2, 0.f);
    float c3 = cm_b3[lane];
#pragma unroll 8
    for (int k = 0; k < 64; ++k) c3 = fmaf(sF[k], cm_W3[(k << 6) + lane], c3);
    out[(size_t)b * 64 + lane] = fmaxf(c3, 0.f);
  }
}

extern "C" void kernel_launch(void* const* d_in, const int* in_sizes, int n_in,
                              void* d_out, int out_size, void* d_ws, size_t ws_size,
                              hipStream_t stream) {
  const int* uids = (const int*)d_in[0];
  const int* u_item_pad = (const int*)d_in[1];
  const int* u_user_pad = (const int*)d_in[2];
  const int* u_user_item_pad = (const int*)d_in[3];
  const float* user_table = (const float*)d_in[4];
  const float* item_table = (const float*)d_in[5];
  const float* rate_table = (const float*)d_in[6];
  const float* gv_W1 = (const float*)d_in[7];
  const float* gv_b1 = (const float*)d_in[8];
  const float* gv_W2 = (const float*)d_in[9];
  const float* gv_b2 = (const float*)d_in[10];
  const float* atti_W1 = (const float*)d_in[11];
  const float* atti_b1 = (const float*)d_in[12];
  const float* atti_W2 = (const float*)d_in[13];
  const float* atti_b2 = (const float*)d_in[14];
  const float* agg_W = (const float*)d_in[15];
  const float* agg_b = (const float*)d_in[16];
  const float* attu_W1 = (const float*)d_in[17];
  const float* attu_b1 = (const float*)d_in[18];
  const float* attu_W2 = (const float*)d_in[19];
  const float* attu_b2 = (const float*)d_in[20];
  const float* aggn_W = (const float*)d_in[21];
  const float* aggn_b = (const float*)d_in[22];
  const float* cm_W1 = (const float*)d_in[23];
  const float* cm_b1 = (const float*)d_in[24];
  const float* cm_W2 = (const float*)d_in[25];
  const float* cm_b2 = (const float*)d_in[26];
  const float* cm_W3 = (const float*)d_in[27];
  const float* cm_b3 = (const float*)d_in[28];
  float* out = (float*)d_out;

  float* hoI = (float*)d_ws;                 // 512*40*64 floats
  float* hiI = hoI + (size_t)512 * 40 * 64;  // 512*64 floats

  // S-branch: 512 blocks, NG=40 groups (P=40 -> padded G=48).
  agg_kernel<<<512, 384, 0, stream>>>(40, 40, 48, u_user_item_pad, u_user_pad,
                                      user_table, item_table, rate_table,
                                      gv_W1, gv_b1, gv_W2, gv_b2,
                                      atti_W1, atti_b1, atti_W2, atti_b2,
                                      agg_W, agg_b, hoI);
  // I-branch: 512 blocks, NG=1 group (P=100 -> padded G=128).
  agg_kernel<<<512, 384, 0, stream>>>(1, 100, 128, u_item_pad, uids,
                                      user_table, item_table, rate_table,
                                      gv_W1, gv_b1, gv_W2, gv_b2,
                                      atti_W1, atti_b1, atti_W2, atti_b2,
                                      agg_W, agg_b, hiI);
  // Beta attention + h_iS + final MLP.
  stage2_kernel<<<512, 256, 0, stream>>>(u_user_pad, user_table, hoI, hiI,
                                         attu_W1, attu_b1, attu_W2, attu_b2,
                                         aggn_W, aggn_b,
                                         cm_W1, cm_b1, cm_W2, cm_b2, cm_W3, cm_b3,
                                         out);
}

// Round 4
// 413.348 us; speedup vs baseline: 45.8171x; 1.1639x over previous
//
#include <hip/hip_runtime.h>
#include <math.h>

#define EPSV 1e-10f
#define CH 64

typedef _Float16 f16x8 __attribute__((ext_vector_type(8)));
typedef float f32x4 __attribute__((ext_vector_type(4)));

// ---------------- LDS layout (bytes) ----------------
#define OFF_W1T   0        // 16384 f16 W1t swz          (phase0: AW1ut f32 64x64)
#define OFF_W2T   16384    // 8192  f16 W2t
#define OFF_AW1X  24576    // 8192  f16 AW1x t
#define OFF_X     32768    // 16384 = 64 rows * 256B f16 (phase0: uS f32 NG*64)
#define OFF_V     49152    // 2048 = 8*64 f32
#define OFF_NUM   51200    // 512  2*64 f32
#define OFF_DEN   51712    // 16
#define OFF_MASK  51728    // 256 = 64 f32
#define OFF_B1    51984    // 256
#define OFF_B2    52240    // 256
#define OFF_AB1   52496    // 256
#define OFF_AW2   52752    // 256
#define OFF_AB2   53008    // 16
#define SMEM_SZ   53024    // < 54613 -> 3 blocks/CU

// ---------------------------------------------------------------------------
// Merged fused item-aggregation (S-branch blocks [0,nSblk), I-branch after).
// 256 threads = 4 waves; chunk = 64 rows = 4 M-tiles; wave w owns tile w.
// Gathers for chunk c+1 prefetched into registers during compute of chunk c.
// Group accumulator slot = group parity (stable across chunk-straddling).
// ---------------------------------------------------------------------------
__global__ __launch_bounds__(256, 3) void agg_kernel(
    const int nSblk,
    const int* __restrict__ idsS, const int* __restrict__ uidS,
    const int* __restrict__ idsI, const int* __restrict__ uidI,
    const float* __restrict__ user_table, const float* __restrict__ item_table,
    const float* __restrict__ rate_table,
    const float* __restrict__ gv_W1, const float* __restrict__ gv_b1,
    const float* __restrict__ gv_W2, const float* __restrict__ gv_b2,
    const float* __restrict__ atti_W1, const float* __restrict__ atti_b1,
    const float* __restrict__ atti_W2, const float* __restrict__ atti_b2,
    const float* __restrict__ agg_W, const float* __restrict__ agg_b,
    float* __restrict__ outS, float* __restrict__ outI) {
  __shared__ __align__(16) char smem[SMEM_SZ];
  const int tid = threadIdx.x;
  const int wave = tid >> 6, lane = tid & 63;
  const int quad = lane >> 4, mrow = lane & 15;

  const bool isS = (int)blockIdx.x < nSblk;
  const int NG = isS ? 8 : 1;
  const int P = isS ? 40 : 100;
  const int G = isS ? 48 : 128;
  const int* __restrict__ ids = isS ? idsS : idsI;
  const int* __restrict__ uidp = isS ? uidS : uidI;
  float* __restrict__ out = isS ? outS : outI;
  const int gbase = isS ? (int)blockIdx.x * 8 : ((int)blockIdx.x - nSblk);
  const int totRows = NG * G;  // 384 or 128

  float* sV = (float*)(smem + OFF_V);
  float* sNum = (float*)(smem + OFF_NUM);
  float* sDen = (float*)(smem + OFF_DEN);
  float* sMask = (float*)(smem + OFF_MASK);
  char* smX = smem + OFF_X;

  // ---- phase0: stage u embeddings (X region) + AW1u^T f32 (W1T region) ----
  {
    float* uS = (float*)smX;
    float* AU = (float*)(smem + OFF_W1T);
    for (int t = tid; t < NG * 64; t += 256) {
      const int g = t >> 6, f = t & 63;
      uS[t] = user_table[(size_t)uidp[gbase + g] * 64 + f];
    }
    for (int t = tid; t < 4096; t += 256) {
      const int j = t >> 6, k = t & 63;
      AU[j * 64 + ((((k >> 2) ^ (j & 15))) << 2) + (k & 3)] =
          atti_W1[(64 + k) * 64 + j];
    }
    if (tid < 128) sNum[tid] = 0.f;
    if (tid < 2) sDen[tid] = 0.f;
  }
  __syncthreads();
  // ---- phase1: v[g][j] = u[g] . AW1u[:,j] ----
  {
    const float4* u4 = (const float4*)smX;
    const float4* a4 = (const float4*)(smem + OFF_W1T);
    for (int t = tid; t < NG * 64; t += 256) {
      const int g = t >> 6, j = t & 63;
      float s = 0.f;
#pragma unroll 4
      for (int kb = 0; kb < 16; ++kb) {
        const float4 uu = u4[g * 16 + kb];
        const float4 aa = a4[j * 16 + (kb ^ (j & 15))];
        s += uu.x * aa.x + uu.y * aa.y + uu.z * aa.z + uu.w * aa.w;
      }
      sV[t] = s;
    }
  }
  __syncthreads();
  // ---- phase2: f16 weight staging (B-operand layout Wt[n][k], swizzled) ----
  for (int t = tid; t < 1024; t += 256) {  // gv_W1 (128x64)
    const int n = t >> 4, kb = t & 15;
    f16x8 h;
#pragma unroll
    for (int j = 0; j < 8; ++j) h[j] = (_Float16)gv_W1[(kb * 8 + j) * 64 + n];
    *(f16x8*)(smem + OFF_W1T + n * 256 + ((kb ^ (n & 7)) << 4)) = h;
  }
  for (int t = tid; t < 512; t += 256) {  // gv_W2 (64x64)
    const int n = t >> 3, kb = t & 7;
    f16x8 h;
#pragma unroll
    for (int j = 0; j < 8; ++j) h[j] = (_Float16)gv_W2[(kb * 8 + j) * 64 + n];
    *(f16x8*)(smem + OFF_W2T + n * 128 + ((kb ^ (n & 7)) << 4)) = h;
  }
  for (int t = tid; t < 512; t += 256) {  // atti_W1 rows 0..63
    const int n = t >> 3, kb = t & 7;
    f16x8 h;
#pragma unroll
    for (int j = 0; j < 8; ++j) h[j] = (_Float16)atti_W1[(kb * 8 + j) * 64 + n];
    *(f16x8*)(smem + OFF_AW1X + n * 128 + ((kb ^ (n & 7)) << 4)) = h;
  }
  if (tid < 64) {
    ((float*)(smem + OFF_B1))[tid] = gv_b1[tid];
    ((float*)(smem + OFF_B2))[tid] = gv_b2[tid];
    ((float*)(smem + OFF_AB1))[tid] = atti_b1[tid];
    ((float*)(smem + OFF_AW2))[tid] = atti_W2[tid];
  }
  if (tid == 0) ((float*)(smem + OFF_AB2))[0] = atti_b2[0];

  // ---- gather prefetch state (4 units/thread: unit u = tid + 256k) ----
  float4 pa[4], pb[4];
  float msk[4];
  auto do_prefetch = [&](int c0) {
#pragma unroll
    for (int k = 0; k < 4; ++k) {
      const int u = tid + (k << 8);
      const int r = u >> 4, bb = u & 15;
      const int gr = c0 + r;
      int g, it;
      if (isS) { g = gr / 48; it = gr - g * 48; }
      else     { g = gr >> 7; it = gr & 127; }
      int iid = 0, rid = 0;
      float m = 0.f;
      if (it < P) {
        const int2 pr = ((const int2*)ids)[(size_t)(gbase + g) * P + it];
        iid = pr.x; rid = pr.y;
        m = (pr.x > 0) ? 1.f : 0.f;
      }
      msk[k] = m;
      const float* src = (bb < 8) ? (item_table + (size_t)iid * 64 + bb * 8)
                                  : (rate_table + (size_t)rid * 64 + (bb - 8) * 8);
      pa[k] = ((const float4*)src)[0];
      pb[k] = ((const float4*)src)[1];
    }
  };
  do_prefetch(0);

  const int nc = totRows / CH;
  for (int ci = 0, c0 = 0; ci < nc; ++ci, c0 += CH) {
    __syncthreads();  // B1: X free (prev compute + epilogue done; phase2 done)
    // ---- write X from prefetched registers ----
#pragma unroll
    for (int k = 0; k < 4; ++k) {
      const int u = tid + (k << 8);
      const int r = u >> 4, bb = u & 15;
      f16x8 h;
      h[0] = (_Float16)pa[k].x; h[1] = (_Float16)pa[k].y;
      h[2] = (_Float16)pa[k].z; h[3] = (_Float16)pa[k].w;
      h[4] = (_Float16)pb[k].x; h[5] = (_Float16)pb[k].y;
      h[6] = (_Float16)pb[k].z; h[7] = (_Float16)pb[k].w;
      *(f16x8*)(smX + r * 256 + ((bb ^ (r & 7)) << 4)) = h;
      if (bb == 0) sMask[r] = msk[k];
    }
    __syncthreads();  // B2: X ready
    if (ci + 1 < nc) do_prefetch(c0 + CH);  // loads in flight across compute
    // ---------------- compute: wave = M-tile ----------------
    {
      const int r0 = wave * 16;
      const int arow = r0 + mrow;
      const int sw = arow & 7;
      const int gb = isS ? ((c0 + r0) / 48) : 0;  // block-local group
      const int gl = gb & 1;                      // parity slot
      // layer1: A-frags (k = quad*8 + 32*ks)
      f16x8 a1[4];
#pragma unroll
      for (int ks = 0; ks < 4; ++ks)
        a1[ks] = *(const f16x8*)(smX + arow * 256 + (((quad + ks * 4) ^ sw) << 4));
      const float* sB1f = (const float*)(smem + OFF_B1);
#pragma unroll
      for (int nt = 0; nt < 4; ++nt) {
        f32x4 c = {0.f, 0.f, 0.f, 0.f};
        const int n = nt * 16 + mrow;
#pragma unroll
        for (int ks = 0; ks < 4; ++ks) {
          const f16x8 b = *(const f16x8*)(smem + OFF_W1T + n * 256 +
                                          (((quad + ks * 4) ^ (n & 7)) << 4));
          c = __builtin_amdgcn_mfma_f32_16x16x32_f16(a1[ks], b, c, 0, 0, 0);
        }
        const float bia = sB1f[n];
#pragma unroll
        for (int rg = 0; rg < 4; ++rg) {  // D: row = quad*4+rg, col = n
          const int rw = r0 + quad * 4 + rg;
          const float h = fmaxf(c[rg] + bia, 0.f);
          *(_Float16*)(smX + rw * 256 + (((n >> 3) ^ (rw & 7)) << 4) +
                       ((n & 7) << 1)) = (_Float16)h;
        }
      }
      // layer2: A from H (cols 0..63)
      f16x8 a2[2];
#pragma unroll
      for (int ks = 0; ks < 2; ++ks)
        a2[ks] = *(const f16x8*)(smX + arow * 256 + (((quad + ks * 4) ^ sw) << 4));
      const float* sB2f = (const float*)(smem + OFF_B2);
      f32x4 x2a[4];
#pragma unroll
      for (int nt = 0; nt < 4; ++nt) {
        f32x4 c = {0.f, 0.f, 0.f, 0.f};
        const int n = nt * 16 + mrow;
#pragma unroll
        for (int ks = 0; ks < 2; ++ks) {
          const f16x8 b = *(const f16x8*)(smem + OFF_W2T + n * 128 +
                                          (((quad + ks * 4) ^ (n & 7)) << 4));
          c = __builtin_amdgcn_mfma_f32_16x16x32_f16(a2[ks], b, c, 0, 0, 0);
        }
        const float bia = sB2f[n];
#pragma unroll
        for (int rg = 0; rg < 4; ++rg) c[rg] += bia;
        x2a[nt] = c;
#pragma unroll
        for (int rg = 0; rg < 4; ++rg) {
          const int rw = r0 + quad * 4 + rg;
          const int cc = 64 + n;
          *(_Float16*)(smX + rw * 256 + (((cc >> 3) ^ (rw & 7)) << 4) +
                       ((cc & 7) << 1)) = (_Float16)c[rg];
        }
      }
      // att layer1: A from x_ia f16 (cols 64..127)
      f16x8 a3[2];
#pragma unroll
      for (int ks = 0; ks < 2; ++ks)
        a3[ks] = *(const f16x8*)(smX + arow * 256 +
                                 (((8 + quad + ks * 4) ^ sw) << 4));
      float mk[4];
#pragma unroll
      for (int rg = 0; rg < 4; ++rg) mk[rg] = sMask[r0 + quad * 4 + rg];
      const float* sAB1f = (const float*)(smem + OFF_AB1);
      const float* sAW2f = (const float*)(smem + OFF_AW2);
      float tl[4] = {0.f, 0.f, 0.f, 0.f};
#pragma unroll
      for (int nt = 0; nt < 4; ++nt) {
        f32x4 c = {0.f, 0.f, 0.f, 0.f};
        const int n = nt * 16 + mrow;
#pragma unroll
        for (int ks = 0; ks < 2; ++ks) {
          const f16x8 b = *(const f16x8*)(smem + OFF_AW1X + n * 128 +
                                          (((quad + ks * 4) ^ (n & 7)) << 4));
          c = __builtin_amdgcn_mfma_f32_16x16x32_f16(a3[ks], b, c, 0, 0, 0);
        }
        const float vb = sV[gb * 64 + n];
        const float b1a = sAB1f[n];
        const float w2 = sAW2f[n];
#pragma unroll
        for (int rg = 0; rg < 4; ++rg) {
          const float h = fmaxf(c[rg] + b1a + mk[rg] * vb, 0.f);
          tl[rg] = fmaf(h, w2, tl[rg]);
        }
      }
      const float ab2v = ((const float*)(smem + OFF_AB2))[0];
      float e[4], dsum = 0.f;
#pragma unroll
      for (int rg = 0; rg < 4; ++rg) {
        float t = tl[rg];
        t += __shfl_xor(t, 1); t += __shfl_xor(t, 2);
        t += __shfl_xor(t, 4); t += __shfl_xor(t, 8);
        e[rg] = __expf(t + ab2v) * mk[rg];
        dsum += e[rg];
      }
      dsum += __shfl_xor(dsum, 16); dsum += __shfl_xor(dsum, 32);
      if (lane == 0) atomicAdd(sDen + gl, dsum);
#pragma unroll
      for (int nt = 0; nt < 4; ++nt) {
        float s = e[0] * x2a[nt][0] + e[1] * x2a[nt][1] +
                  e[2] * x2a[nt][2] + e[3] * x2a[nt][3];
        s += __shfl_xor(s, 16); s += __shfl_xor(s, 32);
        if (quad == 0) atomicAdd(sNum + gl * 64 + nt * 16 + mrow, s);
      }
    }
    __syncthreads();  // B3: sNum/sDen stable
    // ---- epilogue for groups completing in this chunk ----
    if (wave < 2) {
      const int g = (isS ? (c0 / 48) : 0) + wave;
      const int gend = (g + 1) * G;
      if (g < NG && gend > c0 && gend <= c0 + CH) {
        const int slot = g & 1;
        const float rd = 1.f / (sDen[slot] + EPSV);
        float acc = 0.f;
#pragma unroll 8
        for (int k = 0; k < 64; ++k)
          acc = fmaf(sNum[slot * 64 + k], agg_W[k * 64 + lane], acc);
        out[(size_t)(gbase + g) * 64 + lane] = fmaxf(acc * rd + agg_b[lane], 0.f);
        sNum[slot * 64 + lane] = 0.f;
        if (lane == 0) sDen[slot] = 0.f;
      }
    }
  }
}

// ---------------------------------------------------------------------------
// stage2 helpers
// ---------------------------------------------------------------------------
template <int K>
__device__ __forceinline__ void load_wt_swz(float* dst, const float* __restrict__ W) {
  constexpr int NB = K / 4;
  for (int idx = threadIdx.x; idx < 64 * NB; idx += blockDim.x) {
    const int j = idx / NB;
    const int kb = idx % NB;
    float4 v;
    v.x = W[(4 * kb + 0) * 64 + j];
    v.y = W[(4 * kb + 1) * 64 + j];
    v.z = W[(4 * kb + 2) * 64 + j];
    v.w = W[(4 * kb + 3) * 64 + j];
    reinterpret_cast<float4*>(dst)[j * NB + (kb ^ (j & 7))] = v;
  }
}

__device__ __forceinline__ float dot4(float4 a, float4 b) {
  return a.x * b.x + a.y * b.y + a.z * b.z + a.w * b.w;
}

__device__ __forceinline__ float wave_sum(float t) {
#pragma unroll
  for (int off = 32; off > 0; off >>= 1) t += __shfl_xor(t, off, 64);
  return t;
}

// ---------------------------------------------------------------------------
// Kernel 2: beta attention + h_iS + final 3-layer MLP (matvecs k-split over
// the 4 waves to shorten the serial tail).
// ---------------------------------------------------------------------------
__global__ __launch_bounds__(256, 2) void stage2_kernel(
    const int* __restrict__ u_user_pad, const float* __restrict__ user_table,
    const float* __restrict__ hoI, const float* __restrict__ hiI,
    const float* __restrict__ attu_W1, const float* __restrict__ attu_b1,
    const float* __restrict__ attu_W2, const float* __restrict__ attu_b2,
    const float* __restrict__ aggn_W, const float* __restrict__ aggn_b,
    const float* __restrict__ cm_W1, const float* __restrict__ cm_b1,
    const float* __restrict__ cm_W2, const float* __restrict__ cm_b2,
    const float* __restrict__ cm_W3, const float* __restrict__ cm_b3,
    float* __restrict__ out) {
  __shared__ __align__(16) float sW1[64 * 128];
  __shared__ float sW2v[64], sB1[64];
  __shared__ float sB2s;
  __shared__ __align__(16) float sH[40 * 64];
  __shared__ __align__(16) float sN[40 * 64];
  __shared__ float sMask[40];
  __shared__ float sPart[4 * 64];
  __shared__ float sPartD[4];
  __shared__ float sF[128], sG[64];

  const int b = blockIdx.x;
  const int tid = threadIdx.x;
  const int wave = tid >> 6;
  const int lane = tid & 63;
  const int swz = lane & 7;

  load_wt_swz<128>(sW1, attu_W1);
  if (tid < 64) {
    sW2v[tid] = attu_W2[tid];
    sB1[tid] = attu_b1[tid];
  }
  if (tid == 0) sB2s = attu_b2[0];
  for (int idx = tid; idx < 40 * 16; idx += 256)
    reinterpret_cast<float4*>(sH)[idx] =
        reinterpret_cast<const float4*>(hoI)[(size_t)b * 40 * 16 + idx];
  for (int idx = tid; idx < 40 * 16; idx += 256) {
    const int q = idx >> 4, fb = idx & 15;
    const int uid = u_user_pad[b * 40 + q];
    reinterpret_cast<float4*>(sN)[idx] =
        reinterpret_cast<const float4*>(user_table)[(size_t)uid * 16 + fb];
  }
  if (tid < 40) sMask[tid] = u_user_pad[b * 40 + tid] > 0 ? 1.f : 0.f;
  __syncthreads();

  float numer = 0.f, denom = 0.f;
#pragma unroll
  for (int i = 0; i < 10; ++i) {
    const int q = wave + (i << 2);
    float acc = sB1[lane];
#pragma unroll 8
    for (int kb = 0; kb < 16; ++kb) {
      float4 w = reinterpret_cast<const float4*>(sW1)[lane * 32 + (kb ^ swz)];
      float4 x = reinterpret_cast<const float4*>(sH)[q * 16 + kb];
      acc += dot4(w, x);
    }
#pragma unroll 8
    for (int kb = 16; kb < 32; ++kb) {
      float4 w = reinterpret_cast<const float4*>(sW1)[lane * 32 + (kb ^ swz)];
      float4 x = reinterpret_cast<const float4*>(sN)[q * 16 + (kb - 16)];
      acc += dot4(w, x);
    }
    const float tsum = wave_sum(fmaxf(acc, 0.f) * sW2v[lane]);
    const float e = __expf(tsum + sB2s) * sMask[q];
    denom += e;
    numer = fmaf(e, sH[q * 64 + lane], numer);
  }

  sPart[(wave << 6) + lane] = numer;
  if (lane == 0) sPartD[wave] = denom;
  __syncthreads();
  if (wave == 0) {
    const float n = sPart[lane] + sPart[64 + lane] + sPart[128 + lane] + sPart[192 + lane];
    const float d = sPartD[0] + sPartD[1] + sPartD[2] + sPartD[3];
    sG[lane] = n / (d + EPSV);                  // h_agg
    sF[lane] = hiI[(size_t)b * 64 + lane];      // h_iI half of concat
  }
  __syncthreads();
  // aggn: K=64, in sG -> hiS = sF[64+lane]
  {
    float p = 0.f;
    const int k0 = wave << 4;
#pragma unroll
    for (int k = 0; k < 16; ++k) p = fmaf(sG[k0 + k], aggn_W[((k0 + k) << 6) + lane], p);
    sPart[(wave << 6) + lane] = p;
  }
  __syncthreads();
  if (wave == 0) {
    const float a = aggn_b[lane] + sPart[lane] + sPart[64 + lane] +
                    sPart[128 + lane] + sPart[192 + lane];
    sF[64 + lane] = fmaxf(a, 0.f);
  }
  __syncthreads();
  // cm1: K=128, in sF -> sG
  {
    float p = 0.f;
    const int k0 = wave << 5;
#pragma unroll
    for (int k = 0; k < 32; ++k) p = fmaf(sF[k0 + k], cm_W1[((k0 + k) << 6) + lane], p);
    sPart[(wave << 6) + lane] = p;
  }
  __syncthreads();
  if (wave == 0) {
    const float a = cm_b1[lane] + sPart[lane] + sPart[64 + lane] +
                    sPart[128 + lane] + sPart[192 + lane];
    sG[lane] = fmaxf(a, 0.f);
  }
  __syncthreads();
  // cm2: K=64, in sG -> sF[0..63]
  {
    float p = 0.f;
    const int k0 = wave << 4;
#pragma unroll
    for (int k = 0; k < 16; ++k) p = fmaf(sG[k0 + k], cm_W2[((k0 + k) << 6) + lane], p);
    sPart[(wave << 6) + lane] = p;
  }
  __syncthreads();
  if (wave == 0) {
    const float a = cm_b2[lane] + sPart[lane] + sPart[64 + lane] +
                    sPart[128 + lane] + sPart[192 + lane];
    sF[lane] = fmaxf(a, 0.f);
  }
  __syncthreads();
  // cm3: K=64, in sF[0..63] -> out
  {
    float p = 0.f;
    const int k0 = wave << 4;
#pragma unroll
    for (int k = 0; k < 16; ++k) p = fmaf(sF[k0 + k], cm_W3[((k0 + k) << 6) + lane], p);
    sPart[(wave << 6) + lane] = p;
  }
  __syncthreads();
  if (wave == 0) {
    const float a = cm_b3[lane] + sPart[lane] + sPart[64 + lane] +
                    sPart[128 + lane] + sPart[192 + lane];
    out[(size_t)b * 64 + lane] = fmaxf(a, 0.f);
  }
}

extern "C" void kernel_launch(void* const* d_in, const int* in_sizes, int n_in,
                              void* d_out, int out_size, void* d_ws, size_t ws_size,
                              hipStream_t stream) {
  const int* uids = (const int*)d_in[0];
  const int* u_item_pad = (const int*)d_in[1];
  const int* u_user_pad = (const int*)d_in[2];
  const int* u_user_item_pad = (const int*)d_in[3];
  const float* user_table = (const float*)d_in[4];
  const float* item_table = (const float*)d_in[5];
  const float* rate_table = (const float*)d_in[6];
  const float* gv_W1 = (const float*)d_in[7];
  const float* gv_b1 = (const float*)d_in[8];
  const float* gv_W2 = (const float*)d_in[9];
  const float* gv_b2 = (const float*)d_in[10];
  const float* atti_W1 = (const float*)d_in[11];
  const float* atti_b1 = (const float*)d_in[12];
  const float* atti_W2 = (const float*)d_in[13];
  const float* atti_b2 = (const float*)d_in[14];
  const float* agg_W = (const float*)d_in[15];
  const float* agg_b = (const float*)d_in[16];
  const float* attu_W1 = (const float*)d_in[17];
  const float* attu_b1 = (const float*)d_in[18];
  const float* attu_W2 = (const float*)d_in[19];
  const float* attu_b2 = (const float*)d_in[20];
  const float* aggn_W = (const float*)d_in[21];
  const float* aggn_b = (const float*)d_in[22];
  const float* cm_W1 = (const float*)d_in[23];
  const float* cm_b1 = (const float*)d_in[24];
  const float* cm_W2 = (const float*)d_in[25];
  const float* cm_b2 = (const float*)d_in[26];
  const float* cm_W3 = (const float*)d_in[27];
  const float* cm_b3 = (const float*)d_in[28];
  float* out = (float*)d_out;

  float* hoI = (float*)d_ws;                 // 512*40*64 floats
  float* hiI = hoI + (size_t)512 * 40 * 64;  // 512*64 floats

  // Merged S (2560 blocks, NG=8) + I (512 blocks, NG=1) aggregation.
  agg_kernel<<<2560 + 512, 256, 0, stream>>>(
      2560, u_user_item_pad, u_user_pad, u_item_pad, uids,
      user_table, item_table, rate_table,
      gv_W1, gv_b1, gv_W2, gv_b2,
      atti_W1, atti_b1, atti_W2, atti_b2,
      agg_W, agg_b, hoI, hiI);
  // Beta attention + h_iS + final MLP.
  stage2_kernel<<<512, 256, 0, stream>>>(u_user_pad, user_table, hoI, hiI,
                                         attu_W1, attu_b1, attu_W2, attu_b2,
                                         aggn_W, aggn_b,
                                         cm_W1, cm_b1, cm_W2, cm_b2, cm_W3, cm_b3,
                                         out);
}

// Round 5
// 327.042 us; speedup vs baseline: 57.9082x; 1.2639x over previous
//
#include <hip/hip_runtime.h>
#include <math.h>

#define EPSV 1e-10f

typedef _Float16 f16x8 __attribute__((ext_vector_type(8)));
typedef _Float16 f16x4 __attribute__((ext_vector_type(4)));
typedef float f32x4 __attribute__((ext_vector_type(4)));

// ---------------- LDS layout (bytes) ----------------
#define OFF_W1T  0       // 16384: W1t[n][k] f16, 16B-block swz ^(n&7)  (P0: AU f32)
#define OFF_W2T  16384   // 8192:  W2t[n2][h] f16 swz
#define OFF_M2T  24576   // 8192:  M2t[n3][h] f16 swz (M2 = W2 . AW1x)
#define OFF_X    32768   // 16384: 4 wave-slots x 16 rows x 256B (P2a: AW1xT f32 64x64)
#define OFF_V    49152   // 2048:  sV[g][n] = u[g] . AW1u
#define OFF_MASK 51200   // 256:   4 waves x 16 rows
#define OFF_CST  51456   // 256:   cst[n3] = ab1 + b2 . AW1x
#define OFF_CS   51712   // 1024:  4 waves x 64 f32 (epilogue c vector)
#define SMEM_SZ  52736   // <= 54613 -> 3 blocks/CU

__device__ __forceinline__ f16x8 cvt_f16x8(const float4 a, const float4 b) {
  f16x8 h;
  h[0] = (_Float16)a.x; h[1] = (_Float16)a.y; h[2] = (_Float16)a.z; h[3] = (_Float16)a.w;
  h[4] = (_Float16)b.x; h[5] = (_Float16)b.y; h[6] = (_Float16)b.z; h[7] = (_Float16)b.w;
  return h;
}

// ---------------------------------------------------------------------------
// Fused item-aggregation. S-branch blocks [0,nSblk): 8 groups (G=48,P=40),
// I-branch blocks after: 4 groups (G=128,P=100). 256 thr = 4 waves.
// A WAVE OWNS WHOLE GROUPS (S: groups w,w+4 x 3 tiles; I: group w x 8 tiles):
// zero __syncthreads in the main loop; numer/denom live in registers.
// Layer1 computed transposed (A=W1^T, B=In) -> H^T written in-place over the
// item-half of the wave's In rows with ds_write_b64. Attention layer folded:
// logits = H.(W2.AW1x) + cst + mask*v, so X = H.W2+b2 stays in f32 regs for
// the numerator only.
// ---------------------------------------------------------------------------
__global__ __launch_bounds__(256, 3) void agg_kernel(
    const int nSblk,
    const int* __restrict__ idsS, const int* __restrict__ uidS,
    const int* __restrict__ idsI, const int* __restrict__ uidI,
    const float* __restrict__ user_table, const float* __restrict__ item_table,
    const float* __restrict__ rate_table,
    const float* __restrict__ gv_W1, const float* __restrict__ gv_b1,
    const float* __restrict__ gv_W2, const float* __restrict__ gv_b2,
    const float* __restrict__ atti_W1, const float* __restrict__ atti_b1,
    const float* __restrict__ atti_W2, const float* __restrict__ atti_b2,
    const float* __restrict__ agg_W, const float* __restrict__ agg_b,
    float* __restrict__ outS, float* __restrict__ outI) {
  __shared__ __align__(16) char smem[SMEM_SZ];
  const int tid = threadIdx.x;
  const int wave = tid >> 6, lane = tid & 63;
  const int quad = lane >> 4, mrow = lane & 15;

  const bool isS = (int)blockIdx.x < nSblk;
  const int NG = isS ? 8 : 4;
  const int P = isS ? 40 : 100;
  const int nGrp = isS ? 2 : 1;  // groups per wave
  const int tpg = isS ? 3 : 8;   // 16-row tiles per group
  const int* __restrict__ ids = isS ? idsS : idsI;
  const int* __restrict__ uidp = isS ? uidS : uidI;
  float* __restrict__ out = isS ? outS : outI;
  const int gbase = isS ? (int)blockIdx.x * 8 : ((int)blockIdx.x - nSblk) * 4;

  float* sV = (float*)(smem + OFF_V);
  float* sMaskF = (float*)(smem + OFF_MASK);
  float* sCst = (float*)(smem + OFF_CST);
  char* smX = smem + OFF_X;
  char* smXw = smX + wave * 16 * 256;  // wave-private 16 rows
  float* csW = (float*)(smem + OFF_CS) + wave * 64;

  // ---- P0: uS (X region) + AU = AW1u^T f32 (W1T region, f4-swizzled) ----
  {
    float* uS = (float*)smX;
    float* AU = (float*)(smem + OFF_W1T);
    for (int t = tid; t < NG * 64; t += 256) {
      const int g = t >> 6, f = t & 63;
      uS[t] = user_table[(size_t)uidp[gbase + g] * 64 + f];
    }
    for (int o = tid; o < 1024; o += 256) {  // AU[j][k] = atti_W1[64+k][j]
      const int k = o >> 4, fb = o & 15;
      const float4 v = ((const float4*)(atti_W1 + (64 + k) * 64))[fb];
      const float* vp = (const float*)&v;
#pragma unroll
      for (int c = 0; c < 4; ++c) {
        const int j = fb * 4 + c;
        AU[j * 64 + (((k >> 2) ^ (j & 15)) << 2) + (k & 3)] = vp[c];
      }
    }
  }
  __syncthreads();
  // ---- P1: v[g][j] = u[g] . AW1u[:,j] ----
  {
    const float4* u4 = (const float4*)smX;
    const float4* a4 = (const float4*)(smem + OFF_W1T);
    for (int t = tid; t < NG * 64; t += 256) {
      const int g = t >> 6, j = t & 63;
      float s = 0.f;
#pragma unroll 4
      for (int kb = 0; kb < 16; ++kb) {
        const float4 uu = u4[g * 16 + kb];
        const float4 aa = a4[j * 16 + (kb ^ (j & 15))];
        s += uu.x * aa.x + uu.y * aa.y + uu.z * aa.z + uu.w * aa.w;
      }
      sV[t] = s;
    }
  }
  __syncthreads();
  // ---- P2a: AW1xT f32 (X region), W1T/W2T f16 staging (coalesced reads) ----
  {
    float* AX = (float*)smX;  // AX[n3][j] = atti_W1[j][n3], 64-float rows
    for (int o = tid; o < 1024; o += 256) {
      const int j = o >> 4, fb = o & 15;
      const float4 v = ((const float4*)(atti_W1 + j * 64))[fb];
      const float* vp = (const float*)&v;
#pragma unroll
      for (int c = 0; c < 4; ++c) AX[(fb * 4 + c) * 64 + j] = vp[c];
    }
    for (int o = tid; o < 2048; o += 256) {  // W1T[n][k], k in 0..127
      const int k = o >> 4, fb = o & 15;
      const float4 v = ((const float4*)(gv_W1 + k * 64))[fb];
      const float* vp = (const float*)&v;
#pragma unroll
      for (int c = 0; c < 4; ++c) {
        const int n = fb * 4 + c;
        *(_Float16*)(smem + OFF_W1T + n * 256 + ((((k >> 3) ^ (n & 7))) << 4) +
                     ((k & 7) << 1)) = (_Float16)vp[c];
      }
    }
    for (int o = tid; o < 1024; o += 256) {  // W2T[n2][h]
      const int h = o >> 4, fb = o & 15;
      const float4 v = ((const float4*)(gv_W2 + h * 64))[fb];
      const float* vp = (const float*)&v;
#pragma unroll
      for (int c = 0; c < 4; ++c) {
        const int n = fb * 4 + c;
        *(_Float16*)(smem + OFF_W2T + n * 128 + ((((h >> 3) ^ (n & 7))) << 4) +
                     ((h & 7) << 1)) = (_Float16)vp[c];
      }
    }
  }
  // per-lane constant preloads (global, L2-hot)
  float b1r[16], b2v[4], aw2v[4];
#pragma unroll
  for (int nt = 0; nt < 4; ++nt) {
#pragma unroll
    for (int rg = 0; rg < 4; ++rg) b1r[nt * 4 + rg] = gv_b1[nt * 16 + quad * 4 + rg];
    b2v[nt] = gv_b2[nt * 16 + mrow];
    aw2v[nt] = atti_W2[nt * 16 + mrow];
  }
  const float ab2 = atti_b2[0];

  // ---- gather prefetch (wave-private tile: unit = lane + 64k) ----
  float4 pa[4], pb[4];
  float msk[4];
  auto do_prefetch = [&](int gi2, int tt2) {
    const int g2 = gbase + wave + 4 * gi2;
#pragma unroll
    for (int k = 0; k < 4; ++k) {
      const int it = tt2 * 16 + quad + 4 * k;
      int iid = 0, rid = 0;
      float m = 0.f;
      if (it < P) {
        const int2 pr = ((const int2*)ids)[(size_t)g2 * P + it];
        iid = pr.x; rid = pr.y;
        m = pr.x > 0 ? 1.f : 0.f;
      }
      msk[k] = m;
      const float* src = (mrow < 8) ? item_table + (size_t)iid * 64 + mrow * 8
                                    : rate_table + (size_t)rid * 64 + (mrow - 8) * 8;
      pa[k] = ((const float4*)src)[0];
      pb[k] = ((const float4*)src)[1];
    }
  };
  do_prefetch(0, 0);  // in flight across P2b
  __syncthreads();    // B3: AW1xT/W1T/W2T ready
  // ---- P2b: M2T via MFMA (wave = n3-tile) + cst ----
  {
    f16x8 aM[2];
#pragma unroll
    for (int ks = 0; ks < 2; ++ks) {
      const float* s = (const float*)smX + (wave * 16 + mrow) * 64 + ks * 32 + quad * 8;
      f16x8 t;
#pragma unroll
      for (int j = 0; j < 8; ++j) t[j] = (_Float16)s[j];
      aM[ks] = t;
    }
#pragma unroll
    for (int ht = 0; ht < 4; ++ht) {
      f32x4 c = {0.f, 0.f, 0.f, 0.f};
#pragma unroll
      for (int ks = 0; ks < 2; ++ks) {
        const float* s = gv_W2 + (ht * 16 + mrow) * 64 + ks * 32 + quad * 8;
        f16x8 b;
#pragma unroll
        for (int j = 0; j < 8; ++j) b[j] = (_Float16)s[j];
        c = __builtin_amdgcn_mfma_f32_16x16x32_f16(aM[ks], b, c, 0, 0, 0);
      }
      const int h = ht * 16 + mrow;
#pragma unroll
      for (int rg = 0; rg < 4; ++rg) {
        const int n3 = wave * 16 + quad * 4 + rg;
        *(_Float16*)(smem + OFF_M2T + n3 * 128 + ((((h >> 3) ^ (n3 & 7))) << 4) +
                     ((h & 7) << 1)) = (_Float16)c[rg];
      }
    }
    if (tid < 64) {
      const float* AX = (const float*)smX;
      float s = atti_b1[tid];
      for (int j = 0; j < 64; ++j) s = fmaf(gv_b2[j], AX[tid * 64 + j], s);
      sCst[tid] = s;
    }
  }
  __syncthreads();  // B4: M2T/cst ready; X region free for staging
  float cstv[4];
#pragma unroll
  for (int nt = 0; nt < 4; ++nt) cstv[nt] = sCst[nt * 16 + mrow];

  // =================== barrier-free main loop ===================
  for (int gi = 0; gi < nGrp; ++gi) {
    const int g = wave + 4 * gi;
    float vv[4];
#pragma unroll
    for (int nt = 0; nt < 4; ++nt) vv[nt] = sV[g * 64 + nt * 16 + mrow];
    float pnum[4] = {0.f, 0.f, 0.f, 0.f};
    float pden = 0.f;
    for (int tt = 0; tt < tpg; ++tt) {
      // stage In tile from prefetched regs (wave-private rows)
#pragma unroll
      for (int k = 0; k < 4; ++k) {
        const int r = quad + 4 * k;
        *(f16x8*)(smXw + r * 256 + ((mrow ^ (r & 7)) << 4)) = cvt_f16x8(pa[k], pb[k]);
        if (mrow == 0) sMaskF[wave * 16 + r] = msk[k];
      }
      // issue next prefetch
      {
        int ngi = gi, ntt = tt + 1;
        if (ntt == tpg) { ntt = 0; ngi = gi + 1; }
        if (ngi < nGrp) do_prefetch(ngi, ntt);
      }
      // B-frags of In (read all 4 ks before Ht overwrites the low half)
      f16x8 bIn[4];
#pragma unroll
      for (int ks = 0; ks < 4; ++ks)
        bIn[ks] = *(const f16x8*)(smXw + mrow * 256 +
                                  (((ks * 4 + quad) ^ (mrow & 7)) << 4));
      // ---- layer1 (transposed): H^T -> in-place b64 writes ----
#pragma unroll
      for (int nt = 0; nt < 4; ++nt) {
        f32x4 c = {0.f, 0.f, 0.f, 0.f};
#pragma unroll
        for (int ks = 0; ks < 4; ++ks) {
          const f16x8 aW = *(const f16x8*)(smem + OFF_W1T + (nt * 16 + mrow) * 256 +
                                           (((ks * 4 + quad) ^ (mrow & 7)) << 4));
          c = __builtin_amdgcn_mfma_f32_16x16x32_f16(aW, bIn[ks], c, 0, 0, 0);
        }
        f16x4 hv;
#pragma unroll
        for (int rg = 0; rg < 4; ++rg)
          hv[rg] = (_Float16)fmaxf(c[rg] + b1r[nt * 4 + rg], 0.f);
        *(f16x4*)(smXw + mrow * 256 +
                  (((nt * 2 + (quad >> 1)) ^ (mrow & 7)) << 4) +
                  ((quad & 1) << 3)) = hv;
      }
      // ---- shared A-frags (H rows) for layer2 + attention ----
      f16x8 a2[2];
#pragma unroll
      for (int ks = 0; ks < 2; ++ks)
        a2[ks] = *(const f16x8*)(smXw + mrow * 256 +
                                 (((ks * 4 + quad) ^ (mrow & 7)) << 4));
      float mk[4];
#pragma unroll
      for (int rg = 0; rg < 4; ++rg) mk[rg] = sMaskF[wave * 16 + quad * 4 + rg];
      f32x4 x2a[4];
      float tl[4] = {0.f, 0.f, 0.f, 0.f};
#pragma unroll
      for (int nt = 0; nt < 4; ++nt) {
        f32x4 c = {0.f, 0.f, 0.f, 0.f}, d = {0.f, 0.f, 0.f, 0.f};
#pragma unroll
        for (int ks = 0; ks < 2; ++ks) {
          const f16x8 bW = *(const f16x8*)(smem + OFF_W2T + (nt * 16 + mrow) * 128 +
                                           (((ks * 4 + quad) ^ (mrow & 7)) << 4));
          c = __builtin_amdgcn_mfma_f32_16x16x32_f16(a2[ks], bW, c, 0, 0, 0);
        }
#pragma unroll
        for (int ks = 0; ks < 2; ++ks) {
          const f16x8 bM = *(const f16x8*)(smem + OFF_M2T + (nt * 16 + mrow) * 128 +
                                           (((ks * 4 + quad) ^ (mrow & 7)) << 4));
          d = __builtin_amdgcn_mfma_f32_16x16x32_f16(a2[ks], bM, d, 0, 0, 0);
        }
#pragma unroll
        for (int rg = 0; rg < 4; ++rg) x2a[nt][rg] = c[rg] + b2v[nt];
#pragma unroll
        for (int rg = 0; rg < 4; ++rg) {
          const float hh = fmaxf(d[rg] + cstv[nt] + mk[rg] * vv[nt], 0.f);
          tl[rg] = fmaf(hh, aw2v[nt], tl[rg]);
        }
      }
      // logits -> e (reduce over mrow within quad), accumulate in regs
      float e[4];
#pragma unroll
      for (int rg = 0; rg < 4; ++rg) {
        float t = tl[rg];
        t += __shfl_xor(t, 1); t += __shfl_xor(t, 2);
        t += __shfl_xor(t, 4); t += __shfl_xor(t, 8);
        e[rg] = __expf(t + ab2) * mk[rg];
        pden += e[rg];
      }
#pragma unroll
      for (int nt = 0; nt < 4; ++nt) {
        pnum[nt] = fmaf(e[0], x2a[nt][0], pnum[nt]);
        pnum[nt] = fmaf(e[1], x2a[nt][1], pnum[nt]);
        pnum[nt] = fmaf(e[2], x2a[nt][2], pnum[nt]);
        pnum[nt] = fmaf(e[3], x2a[nt][3], pnum[nt]);
      }
    }
    // ---- group flush (wave-local): quad-reduce + agg matvec + store ----
    float dsum = pden;
    dsum += __shfl_xor(dsum, 16); dsum += __shfl_xor(dsum, 32);
    const float rd = 1.f / (dsum + EPSV);
#pragma unroll
    for (int nt = 0; nt < 4; ++nt) {
      float s = pnum[nt];
      s += __shfl_xor(s, 16); s += __shfl_xor(s, 32);
      if (quad == 0) csW[nt * 16 + mrow] = s * rd;
    }
    float acc = agg_b[lane];
#pragma unroll 8
    for (int k = 0; k < 64; ++k) acc = fmaf(csW[k], agg_W[k * 64 + lane], acc);
    out[(size_t)(gbase + g) * 64 + lane] = fmaxf(acc, 0.f);
  }
}

// ---------------------------------------------------------------------------
// stage2 helpers
// ---------------------------------------------------------------------------
__device__ __forceinline__ float dot4(float4 a, float4 b) {
  return a.x * b.x + a.y * b.y + a.z * b.z + a.w * b.w;
}

__device__ __forceinline__ float wave_sum(float t) {
#pragma unroll
  for (int off = 32; off > 0; off >>= 1) t += __shfl_xor(t, off, 64);
  return t;
}

// ---------------------------------------------------------------------------
// Kernel 2: beta attention + h_iS + final 3-layer MLP. Coalesced W1 staging
// (float4 row reads + LDS scatter); matvec tail k-split over 4 waves.
// ---------------------------------------------------------------------------
__global__ __launch_bounds__(256, 1) void stage2_kernel(
    const int* __restrict__ u_user_pad, const float* __restrict__ user_table,
    const float* __restrict__ hoI, const float* __restrict__ hiI,
    const float* __restrict__ attu_W1, const float* __restrict__ attu_b1,
    const float* __restrict__ attu_W2, const float* __restrict__ attu_b2,
    const float* __restrict__ aggn_W, const float* __restrict__ aggn_b,
    const float* __restrict__ cm_W1, const float* __restrict__ cm_b1,
    const float* __restrict__ cm_W2, const float* __restrict__ cm_b2,
    const float* __restrict__ cm_W3, const float* __restrict__ cm_b3,
    float* __restrict__ out) {
  __shared__ __align__(16) float sW1[64 * 128];
  __shared__ float sW2v[64], sB1[64];
  __shared__ float sB2s;
  __shared__ __align__(16) float sH[40 * 64];
  __shared__ __align__(16) float sN[40 * 64];
  __shared__ float sMask[40];
  __shared__ float sPart[4 * 64];
  __shared__ float sPartD[4];
  __shared__ float sF[128], sG[64];

  const int b = blockIdx.x;
  const int tid = threadIdx.x;
  const int wave = tid >> 6;
  const int lane = tid & 63;
  const int swz = lane & 7;

  // coalesced staging of attu_W1 -> sW1[j][k] (f4-swizzled)
  for (int idx = tid; idx < 2048; idx += 256) {
    const int k = idx >> 4, fb = idx & 15;
    const float4 v = ((const float4*)(attu_W1 + k * 64))[fb];
    const float* vp = (const float*)&v;
#pragma unroll
    for (int c = 0; c < 4; ++c) {
      const int j = fb * 4 + c;
      sW1[j * 128 + (((k >> 2) ^ (j & 7)) << 2) + (k & 3)] = vp[c];
    }
  }
  if (tid < 64) {
    sW2v[tid] = attu_W2[tid];
    sB1[tid] = attu_b1[tid];
  }
  if (tid == 0) sB2s = attu_b2[0];
  for (int idx = tid; idx < 40 * 16; idx += 256)
    reinterpret_cast<float4*>(sH)[idx] =
        reinterpret_cast<const float4*>(hoI)[(size_t)b * 40 * 16 + idx];
  for (int idx = tid; idx < 40 * 16; idx += 256) {
    const int q = idx >> 4, fb = idx & 15;
    const int uid = u_user_pad[b * 40 + q];
    reinterpret_cast<float4*>(sN)[idx] =
        reinterpret_cast<const float4*>(user_table)[(size_t)uid * 16 + fb];
  }
  if (tid < 40) sMask[tid] = u_user_pad[b * 40 + tid] > 0 ? 1.f : 0.f;
  __syncthreads();

  float numer = 0.f, denom = 0.f;
#pragma unroll
  for (int i = 0; i < 10; ++i) {
    const int q = wave + (i << 2);
    float acc = sB1[lane];
#pragma unroll 8
    for (int kb = 0; kb < 16; ++kb) {
      float4 w = reinterpret_cast<const float4*>(sW1)[lane * 32 + (kb ^ swz)];
      float4 x = reinterpret_cast<const float4*>(sH)[q * 16 + kb];
      acc += dot4(w, x);
    }
#pragma unroll 8
    for (int kb = 16; kb < 32; ++kb) {
      float4 w = reinterpret_cast<const float4*>(sW1)[lane * 32 + (kb ^ swz)];
      float4 x = reinterpret_cast<const float4*>(sN)[q * 16 + (kb - 16)];
      acc += dot4(w, x);
    }
    const float tsum = wave_sum(fmaxf(acc, 0.f) * sW2v[lane]);
    const float e = __expf(tsum + sB2s) * sMask[q];
    denom += e;
    numer = fmaf(e, sH[q * 64 + lane], numer);
  }

  sPart[(wave << 6) + lane] = numer;
  if (lane == 0) sPartD[wave] = denom;
  __syncthreads();
  if (wave == 0) {
    const float n = sPart[lane] + sPart[64 + lane] + sPart[128 + lane] + sPart[192 + lane];
    const float d = sPartD[0] + sPartD[1] + sPartD[2] + sPartD[3];
    sG[lane] = n / (d + EPSV);
    sF[lane] = hiI[(size_t)b * 64 + lane];
  }
  __syncthreads();
  {
    float p = 0.f;
    const int k0 = wave << 4;
#pragma unroll
    for (int k = 0; k < 16; ++k) p = fmaf(sG[k0 + k], aggn_W[((k0 + k) << 6) + lane], p);
    sPart[(wave << 6) + lane] = p;
  }
  __syncthreads();
  if (wave == 0) {
    const float a = aggn_b[lane] + sPart[lane] + sPart[64 + lane] +
                    sPart[128 + lane] + sPart[192 + lane];
    sF[64 + lane] = fmaxf(a, 0.f);
  }
  __syncthreads();
  {
    float p = 0.f;
    const int k0 = wave << 5;
#pragma unroll
    for (int k = 0; k < 32; ++k) p = fmaf(sF[k0 + k], cm_W1[((k0 + k) << 6) + lane], p);
    sPart[(wave << 6) + lane] = p;
  }
  __syncthreads();
  if (wave == 0) {
    const float a = cm_b1[lane] + sPart[lane] + sPart[64 + lane] +
                    sPart[128 + lane] + sPart[192 + lane];
    sG[lane] = fmaxf(a, 0.f);
  }
  __syncthreads();
  {
    float p = 0.f;
    const int k0 = wave << 4;
#pragma unroll
    for (int k = 0; k < 16; ++k) p = fmaf(sG[k0 + k], cm_W2[((k0 + k) << 6) + lane], p);
    sPart[(wave << 6) + lane] = p;
  }
  __syncthreads();
  if (wave == 0) {
    const float a = cm_b2[lane] + sPart[lane] + sPart[64 + lane] +
                    sPart[128 + lane] + sPart[192 + lane];
    sF[lane] = fmaxf(a, 0.f);
  }
  __syncthreads();
  {
    float p = 0.f;
    const int k0 = wave << 4;
#pragma unroll
    for (int k = 0; k < 16; ++k) p = fmaf(sF[k0 + k], cm_W3[((k0 + k) << 6) + lane], p);
    sPart[(wave << 6) + lane] = p;
  }
  __syncthreads();
  if (wave == 0) {
    const float a = cm_b3[lane] + sPart[lane] + sPart[64 + lane] +
                    sPart[128 + lane] + sPart[192 + lane];
    out[(size_t)b * 64 + lane] = fmaxf(a, 0.f);
  }
}

extern "C" void kernel_launch(void* const* d_in, const int* in_sizes, int n_in,
                              void* d_out, int out_size, void* d_ws, size_t ws_size,
                              hipStream_t stream) {
  const int* uids = (const int*)d_in[0];
  const int* u_item_pad = (const int*)d_in[1];
  const int* u_user_pad = (const int*)d_in[2];
  const int* u_user_item_pad = (const int*)d_in[3];
  const float* user_table = (const float*)d_in[4];
  const float* item_table = (const float*)d_in[5];
  const float* rate_table = (const float*)d_in[6];
  const float* gv_W1 = (const float*)d_in[7];
  const float* gv_b1 = (const float*)d_in[8];
  const float* gv_W2 = (const float*)d_in[9];
  const float* gv_b2 = (const float*)d_in[10];
  const float* atti_W1 = (const float*)d_in[11];
  const float* atti_b1 = (const float*)d_in[12];
  const float* atti_W2 = (const float*)d_in[13];
  const float* atti_b2 = (const float*)d_in[14];
  const float* agg_W = (const float*)d_in[15];
  const float* agg_b = (const float*)d_in[16];
  const float* attu_W1 = (const float*)d_in[17];
  const float* attu_b1 = (const float*)d_in[18];
  const float* attu_W2 = (const float*)d_in[19];
  const float* attu_b2 = (const float*)d_in[20];
  const float* aggn_W = (const float*)d_in[21];
  const float* aggn_b = (const float*)d_in[22];
  const float* cm_W1 = (const float*)d_in[23];
  const float* cm_b1 = (const float*)d_in[24];
  const float* cm_W2 = (const float*)d_in[25];
  const float* cm_b2 = (const float*)d_in[26];
  const float* cm_W3 = (const float*)d_in[27];
  const float* cm_b3 = (const float*)d_in[28];
  float* out = (float*)d_out;

  float* hoI = (float*)d_ws;                 // 512*40*64 floats
  float* hiI = hoI + (size_t)512 * 40 * 64;  // 512*64 floats

  // Merged S (2560 blocks x 8 groups) + I (128 blocks x 4 groups).
  agg_kernel<<<2560 + 128, 256, 0, stream>>>(
      2560, u_user_item_pad, u_user_pad, u_item_pad, uids,
      user_table, item_table, rate_table,
      gv_W1, gv_b1, gv_W2, gv_b2,
      atti_W1, atti_b1, atti_W2, atti_b2,
      agg_W, agg_b, hoI, hiI);
  // Beta attention + h_iS + final MLP.
  stage2_kernel<<<512, 256, 0, stream>>>(u_user_pad, user_table, hoI, hiI,
                                         attu_W1, attu_b1, attu_W2, attu_b2,
                                         aggn_W, aggn_b,
                                         cm_W1, cm_b1, cm_W2, cm_b2, cm_W3, cm_b3,
                                         out);
}

// Round 6
// 305.072 us; speedup vs baseline: 62.0786x; 1.0720x over previous
//
#include <hip/hip_runtime.h>
#include <math.h>

#define EPSV 1e-10f

typedef _Float16 f16x8 __attribute__((ext_vector_type(8)));
typedef _Float16 f16x4 __attribute__((ext_vector_type(4)));
typedef float f32x4 __attribute__((ext_vector_type(4)));

// ---------------- agg LDS layout (bytes) ----------------
#define OFF_W1T  0       // 16384: W1t[n][k] f16 swz      (P0: AU f32 64x64)
#define OFF_W2T  16384   // 8192:  W2t[n2][h] f16 swz
#define OFF_M2T  24576   // 8192:  M2t[n3][h] f16 swz (M2 = W2 . AW1x)
#define OFF_X    32768   // 16384: 4 wave-slots x 16 rows x 256B
                         //        (P0: uS f32; P2a: cst partials 4x64 f32)
#define OFF_V    49152   // 4096:  sV[g][n] = u[g] . AW1u   (16 groups max)
#define OFF_MASK 53248   // 256:   4 waves x 16 rows
#define OFF_CST  53504   // 256:   cst[n3] = ab1 + b2 . AW1x
#define SMEM_SZ  53760   // <= 54613 -> 3 blocks/CU

__device__ __forceinline__ f16x8 cvt_f16x8(const float4 a, const float4 b) {
  f16x8 h;
  h[0] = (_Float16)a.x; h[1] = (_Float16)a.y; h[2] = (_Float16)a.z; h[3] = (_Float16)a.w;
  h[4] = (_Float16)b.x; h[5] = (_Float16)b.y; h[6] = (_Float16)b.z; h[7] = (_Float16)b.w;
  return h;
}

// ---------------------------------------------------------------------------
// Fused item-aggregation. S-blocks [0,nSblk): 16 groups (G=48,P=40, 4/wave);
// I-blocks after: 4 groups (G=128,P=100, 1/wave). 256 thr = 4 waves.
// Wave owns whole groups -> zero __syncthreads in the main loop.
// ---------------------------------------------------------------------------
__global__ __launch_bounds__(256, 3) void agg_kernel(
    const int nSblk,
    const int* __restrict__ idsS, const int* __restrict__ uidS,
    const int* __restrict__ idsI, const int* __restrict__ uidI,
    const float* __restrict__ user_table, const float* __restrict__ item_table,
    const float* __restrict__ rate_table,
    const float* __restrict__ gv_W1, const float* __restrict__ gv_b1,
    const float* __restrict__ gv_W2, const float* __restrict__ gv_b2,
    const float* __restrict__ atti_W1, const float* __restrict__ atti_b1,
    const float* __restrict__ atti_W2, const float* __restrict__ atti_b2,
    const float* __restrict__ agg_W, const float* __restrict__ agg_b,
    float* __restrict__ outS, float* __restrict__ outI) {
  __shared__ __align__(16) char smem[SMEM_SZ];
  const int tid = threadIdx.x;
  const int wave = tid >> 6, lane = tid & 63;
  const int quad = lane >> 4, mrow = lane & 15;

  const bool isS = (int)blockIdx.x < nSblk;
  const int NG = isS ? 16 : 4;
  const int P = isS ? 40 : 100;
  const int nGrp = isS ? 4 : 1;  // groups per wave
  const int tpg = isS ? 3 : 8;   // 16-row tiles per group
  const int* __restrict__ ids = isS ? idsS : idsI;
  const int* __restrict__ uidp = isS ? uidS : uidI;
  float* __restrict__ out = isS ? outS : outI;
  const int gbase = isS ? (int)blockIdx.x * 16 : ((int)blockIdx.x - nSblk) * 4;

  float* sV = (float*)(smem + OFF_V);
  float* sMaskF = (float*)(smem + OFF_MASK);
  float* sCst = (float*)(smem + OFF_CST);
  char* smX = smem + OFF_X;
  char* smXw = smX + wave * 16 * 256;  // wave-private 16 rows
  float* csW = (float*)smXw;           // epilogue c vector (tile is dead then)

  // ---- P0: uS (X region) + AU = AW1u^T f32 (W1T region, f4-swizzled) ----
  {
    float* uS = (float*)smX;
    float* AU = (float*)(smem + OFF_W1T);
    for (int t = tid; t < NG * 64; t += 256) {
      const int g = t >> 6, f = t & 63;
      uS[t] = user_table[(size_t)uidp[gbase + g] * 64 + f];
    }
    for (int o = tid; o < 1024; o += 256) {  // AU[j][k] = atti_W1[64+k][j]
      const int k = o >> 4, fb = o & 15;
      const float4 v = ((const float4*)(atti_W1 + (64 + k) * 64))[fb];
      const float* vp = (const float*)&v;
#pragma unroll
      for (int c = 0; c < 4; ++c) {
        const int j = fb * 4 + c;
        AU[j * 64 + (((k >> 2) ^ (j & 15)) << 2) + (k & 3)] = vp[c];
      }
    }
  }
  __syncthreads();
  // ---- P1: v[g][j] = u[g] . AW1u[:,j] ----
  {
    const float4* u4 = (const float4*)smX;
    const float4* a4 = (const float4*)(smem + OFF_W1T);
    for (int t = tid; t < NG * 64; t += 256) {
      const int g = t >> 6, j = t & 63;
      float s = 0.f;
#pragma unroll 4
      for (int kb = 0; kb < 16; ++kb) {
        const float4 uu = u4[g * 16 + kb];
        const float4 aa = a4[j * 16 + (kb ^ (j & 15))];
        s += uu.x * aa.x + uu.y * aa.y + uu.z * aa.z + uu.w * aa.w;
      }
      sV[t] = s;
    }
  }
  __syncthreads();
  // ---- P2a: W1T/W2T f16 staging (coalesced) + cst partials (global) ----
  {
    for (int o = tid; o < 2048; o += 256) {  // W1T[n][k], k in 0..127
      const int k = o >> 4, fb = o & 15;
      const float4 v = ((const float4*)(gv_W1 + k * 64))[fb];
      const float* vp = (const float*)&v;
#pragma unroll
      for (int c = 0; c < 4; ++c) {
        const int n = fb * 4 + c;
        *(_Float16*)(smem + OFF_W1T + n * 256 + ((((k >> 3) ^ (n & 7))) << 4) +
                     ((k & 7) << 1)) = (_Float16)vp[c];
      }
    }
    for (int o = tid; o < 1024; o += 256) {  // W2T[n2][h]
      const int h = o >> 4, fb = o & 15;
      const float4 v = ((const float4*)(gv_W2 + h * 64))[fb];
      const float* vp = (const float*)&v;
#pragma unroll
      for (int c = 0; c < 4; ++c) {
        const int n = fb * 4 + c;
        *(_Float16*)(smem + OFF_W2T + n * 128 + ((((h >> 3) ^ (n & 7))) << 4) +
                     ((h & 7) << 1)) = (_Float16)vp[c];
      }
    }
    // cst partials: p[jh][n] = sum_{j in jh*16..+16} b2[j]*AW1x[j][n]
    float* sCstP = (float*)smX;  // uS dead after P1
    const int n = tid & 63, jh = tid >> 6;
    float p = 0.f;
#pragma unroll 4
    for (int jj = 0; jj < 16; ++jj) {
      const int j = jh * 16 + jj;
      p = fmaf(gv_b2[j], atti_W1[j * 64 + n], p);
    }
    sCstP[jh * 64 + n] = p;
  }
  // per-lane constant preloads (global, L2-hot)
  float b1r[16], b2v[4], aw2v[4];
#pragma unroll
  for (int nt = 0; nt < 4; ++nt) {
#pragma unroll
    for (int rg = 0; rg < 4; ++rg) b1r[nt * 4 + rg] = gv_b1[nt * 16 + quad * 4 + rg];
    b2v[nt] = gv_b2[nt * 16 + mrow];
    aw2v[nt] = atti_W2[nt * 16 + mrow];
  }
  const float ab2 = atti_b2[0];

  // ---- gather prefetch (wave-private tile) ----
  float4 pa[4], pb[4];
  float msk[4];
  auto do_prefetch = [&](int gi2, int tt2) {
    const int g2 = gbase + wave + 4 * gi2;
#pragma unroll
    for (int k = 0; k < 4; ++k) {
      const int it = tt2 * 16 + quad + 4 * k;
      int iid = 0, rid = 0;
      float m = 0.f;
      if (it < P) {
        const int2 pr = ((const int2*)ids)[(size_t)g2 * P + it];
        iid = pr.x; rid = pr.y;
        m = pr.x > 0 ? 1.f : 0.f;
      }
      msk[k] = m;
      const float* src = (mrow < 8) ? item_table + (size_t)iid * 64 + mrow * 8
                                    : rate_table + (size_t)rid * 64 + (mrow - 8) * 8;
      pa[k] = ((const float4*)src)[0];
      pb[k] = ((const float4*)src)[1];
    }
  };
  do_prefetch(0, 0);  // in flight across P2b
  __syncthreads();    // B3: W1T/W2T/cstP ready
  // ---- P2b: M2T via MFMA (A,B from L2-hot global) + cst final ----
  {
    f16x8 aM[2];
#pragma unroll
    for (int ks = 0; ks < 2; ++ks) {
      f16x8 t;
#pragma unroll
      for (int j = 0; j < 8; ++j)
        t[j] = (_Float16)atti_W1[(ks * 32 + quad * 8 + j) * 64 + (wave * 16 + mrow)];
      aM[ks] = t;
    }
#pragma unroll
    for (int ht = 0; ht < 4; ++ht) {
      f32x4 c = {0.f, 0.f, 0.f, 0.f};
#pragma unroll
      for (int ks = 0; ks < 2; ++ks) {
        const float* s = gv_W2 + (ht * 16 + mrow) * 64 + ks * 32 + quad * 8;
        f16x8 b;
#pragma unroll
        for (int j = 0; j < 8; ++j) b[j] = (_Float16)s[j];
        c = __builtin_amdgcn_mfma_f32_16x16x32_f16(aM[ks], b, c, 0, 0, 0);
      }
      const int h = ht * 16 + mrow;
#pragma unroll
      for (int rg = 0; rg < 4; ++rg) {
        const int n3 = wave * 16 + quad * 4 + rg;
        *(_Float16*)(smem + OFF_M2T + n3 * 128 + ((((h >> 3) ^ (n3 & 7))) << 4) +
                     ((h & 7) << 1)) = (_Float16)c[rg];
      }
    }
    if (tid < 64) {
      const float* sCstP = (const float*)smX;
      sCst[tid] = atti_b1[tid] + sCstP[tid] + sCstP[64 + tid] +
                  sCstP[128 + tid] + sCstP[192 + tid];
    }
  }
  __syncthreads();  // B4: M2T/cst ready; X region free for staging
  float cstv[4];
#pragma unroll
  for (int nt = 0; nt < 4; ++nt) cstv[nt] = sCst[nt * 16 + mrow];

  // =================== barrier-free main loop ===================
  for (int gi = 0; gi < nGrp; ++gi) {
    const int g = wave + 4 * gi;
    float vv[4];
#pragma unroll
    for (int nt = 0; nt < 4; ++nt) vv[nt] = sV[g * 64 + nt * 16 + mrow];
    float pnum[4] = {0.f, 0.f, 0.f, 0.f};
    float pden = 0.f;
    for (int tt = 0; tt < tpg; ++tt) {
      // stage In tile from prefetched regs (wave-private rows)
#pragma unroll
      for (int k = 0; k < 4; ++k) {
        const int r = quad + 4 * k;
        *(f16x8*)(smXw + r * 256 + ((mrow ^ (r & 7)) << 4)) = cvt_f16x8(pa[k], pb[k]);
        if (mrow == 0) sMaskF[wave * 16 + r] = msk[k];
      }
      // issue next prefetch
      {
        int ngi = gi, ntt = tt + 1;
        if (ntt == tpg) { ntt = 0; ngi = gi + 1; }
        if (ngi < nGrp) do_prefetch(ngi, ntt);
      }
      // B-frags of In (read all 4 ks before Ht overwrites the low half)
      f16x8 bIn[4];
#pragma unroll
      for (int ks = 0; ks < 4; ++ks)
        bIn[ks] = *(const f16x8*)(smXw + mrow * 256 +
                                  (((ks * 4 + quad) ^ (mrow & 7)) << 4));
      // ---- layer1 (transposed): H^T -> in-place b64 writes ----
#pragma unroll
      for (int nt = 0; nt < 4; ++nt) {
        f32x4 c = {0.f, 0.f, 0.f, 0.f};
#pragma unroll
        for (int ks = 0; ks < 4; ++ks) {
          const f16x8 aW = *(const f16x8*)(smem + OFF_W1T + (nt * 16 + mrow) * 256 +
                                           (((ks * 4 + quad) ^ (mrow & 7)) << 4));
          c = __builtin_amdgcn_mfma_f32_16x16x32_f16(aW, bIn[ks], c, 0, 0, 0);
        }
        f16x4 hv;
#pragma unroll
        for (int rg = 0; rg < 4; ++rg)
          hv[rg] = (_Float16)fmaxf(c[rg] + b1r[nt * 4 + rg], 0.f);
        *(f16x4*)(smXw + mrow * 256 +
                  (((nt * 2 + (quad >> 1)) ^ (mrow & 7)) << 4) +
                  ((quad & 1) << 3)) = hv;
      }
      // ---- shared A-frags (H rows) for layer2 + attention ----
      f16x8 a2[2];
#pragma unroll
      for (int ks = 0; ks < 2; ++ks)
        a2[ks] = *(const f16x8*)(smXw + mrow * 256 +
                                 (((ks * 4 + quad) ^ (mrow & 7)) << 4));
      float mk[4];
#pragma unroll
      for (int rg = 0; rg < 4; ++rg) mk[rg] = sMaskF[wave * 16 + quad * 4 + rg];
      f32x4 x2a[4];
      float tl[4] = {0.f, 0.f, 0.f, 0.f};
#pragma unroll
      for (int nt = 0; nt < 4; ++nt) {
        f32x4 c = {0.f, 0.f, 0.f, 0.f}, d = {0.f, 0.f, 0.f, 0.f};
#pragma unroll
        for (int ks = 0; ks < 2; ++ks) {
          const f16x8 bW = *(const f16x8*)(smem + OFF_W2T + (nt * 16 + mrow) * 128 +
                                           (((ks * 4 + quad) ^ (mrow & 7)) << 4));
          c = __builtin_amdgcn_mfma_f32_16x16x32_f16(a2[ks], bW, c, 0, 0, 0);
        }
#pragma unroll
        for (int ks = 0; ks < 2; ++ks) {
          const f16x8 bM = *(const f16x8*)(smem + OFF_M2T + (nt * 16 + mrow) * 128 +
                                           (((ks * 4 + quad) ^ (mrow & 7)) << 4));
          d = __builtin_amdgcn_mfma_f32_16x16x32_f16(a2[ks], bM, d, 0, 0, 0);
        }
#pragma unroll
        for (int rg = 0; rg < 4; ++rg) x2a[nt][rg] = c[rg] + b2v[nt];
#pragma unroll
        for (int rg = 0; rg < 4; ++rg) {
          const float hh = fmaxf(d[rg] + cstv[nt] + mk[rg] * vv[nt], 0.f);
          tl[rg] = fmaf(hh, aw2v[nt], tl[rg]);
        }
      }
      // logits -> e (reduce over mrow within quad), accumulate in regs
      float e[4];
#pragma unroll
      for (int rg = 0; rg < 4; ++rg) {
        float t = tl[rg];
        t += __shfl_xor(t, 1); t += __shfl_xor(t, 2);
        t += __shfl_xor(t, 4); t += __shfl_xor(t, 8);
        e[rg] = __expf(t + ab2) * mk[rg];
        pden += e[rg];
      }
#pragma unroll
      for (int nt = 0; nt < 4; ++nt) {
        pnum[nt] = fmaf(e[0], x2a[nt][0], pnum[nt]);
        pnum[nt] = fmaf(e[1], x2a[nt][1], pnum[nt]);
        pnum[nt] = fmaf(e[2], x2a[nt][2], pnum[nt]);
        pnum[nt] = fmaf(e[3], x2a[nt][3], pnum[nt]);
      }
    }
    // ---- group flush (wave-local): quad-reduce + agg matvec + store ----
    float dsum = pden;
    dsum += __shfl_xor(dsum, 16); dsum += __shfl_xor(dsum, 32);
    const float rd = 1.f / (dsum + EPSV);
#pragma unroll
    for (int nt = 0; nt < 4; ++nt) {
      float s = pnum[nt];
      s += __shfl_xor(s, 16); s += __shfl_xor(s, 32);
      if (quad == 0) csW[nt * 16 + mrow] = s * rd;
    }
    float acc = agg_b[lane];
#pragma unroll 8
    for (int k = 0; k < 64; ++k) acc = fmaf(csW[k], agg_W[k * 64 + lane], acc);
    out[(size_t)(gbase + g) * 64 + lane] = fmaxf(acc, 0.f);
  }
}

// ---------------- stage2 LDS layout (bytes) ----------------
#define S2_W1T 0       // 17408: attu_W1^T f16 [n][k], pitch 272 (bank-rotated)
#define S2_X   17408   // 8704:  2 waves x 16 rows x 272B
#define S2_E   26112   // 128:   2 x 16 f32
#define S2_MSK 26240   // 128:   2 x 16 f32
#define S2_HB  26368   // 1536:  2 x 192 f32 (concat/hidden ping-pong)
#define S2_SZ  27904

// ---------------------------------------------------------------------------
// Kernel 2: beta attention (MFMA) + h_iS + final 3-layer MLP.
// 256 blocks x 128 thr; wave w handles b = blockIdx*2 + w, fully autonomously
// (one __syncthreads total, after shared W1T staging).
// ---------------------------------------------------------------------------
__global__ __launch_bounds__(128, 2) void stage2_kernel(
    const int* __restrict__ u_user_pad, const float* __restrict__ user_table,
    const float* __restrict__ hoI, const float* __restrict__ hiI,
    const float* __restrict__ attu_W1, const float* __restrict__ attu_b1,
    const float* __restrict__ attu_W2, const float* __restrict__ attu_b2,
    const float* __restrict__ aggn_W, const float* __restrict__ aggn_b,
    const float* __restrict__ cm_W1, const float* __restrict__ cm_b1,
    const float* __restrict__ cm_W2, const float* __restrict__ cm_b2,
    const float* __restrict__ cm_W3, const float* __restrict__ cm_b3,
    float* __restrict__ out) {
  __shared__ __align__(16) char smem[S2_SZ];
  const int tid = threadIdx.x;
  const int wave = tid >> 6, lane = tid & 63;
  const int quad = lane >> 4, mrow = lane & 15;
  const int b = (int)blockIdx.x * 2 + wave;

  char* sW1 = smem + S2_W1T;
  char* sXw = smem + S2_X + wave * 4352;
  float* sE = (float*)(smem + S2_E) + wave * 16;
  float* sM = (float*)(smem + S2_MSK) + wave * 16;
  float* sB = (float*)(smem + S2_HB) + wave * 192;

  // W1T staging: coalesced float4 row reads, f16 scatter (pitch 272 rotates banks)
  for (int o = tid; o < 2048; o += 128) {
    const int k = o >> 4, fb = o & 15;
    const float4 v = ((const float4*)(attu_W1 + k * 64))[fb];
    const float* vp = (const float*)&v;
#pragma unroll
    for (int c = 0; c < 4; ++c) {
      const int n = fb * 4 + c;
      *(_Float16*)(sW1 + n * 272 + ((k >> 3) << 4) + ((k & 7) << 1)) = (_Float16)vp[c];
    }
  }
  float b1v[4], w2v[4];
#pragma unroll
  for (int nt = 0; nt < 4; ++nt) {
    b1v[nt] = attu_b1[nt * 16 + mrow];
    w2v[nt] = attu_W2[nt * 16 + mrow];
  }
  const float b2s = attu_b2[0];

  // prefetch (4 units/lane: unit = lane + 64k -> row r = u>>4, block bb = u&15)
  float4 pa[4], pb[4];
  float msk[4];
  auto pf = [&](int tt) {
#pragma unroll
    for (int k = 0; k < 4; ++k) {
      const int u = lane + (k << 6);
      const int r = u >> 4, bb = u & 15;
      const int q = tt * 16 + r;
      const int qc = q < 40 ? q : 39;
      int uid = 0;
      float m = 0.f;
      if (q < 40) {
        uid = u_user_pad[b * 40 + q];
        m = uid > 0 ? 1.f : 0.f;
      }
      msk[k] = m;
      const float* src = (bb < 8)
                             ? hoI + ((size_t)b * 40 + qc) * 64 + bb * 8
                             : user_table + (size_t)uid * 64 + (bb - 8) * 8;
      pa[k] = ((const float4*)src)[0];
      pb[k] = ((const float4*)src)[1];
    }
  };
  pf(0);
  __syncthreads();  // W1T ready

  float numer = 0.f, pden = 0.f;
  for (int tt = 0; tt < 3; ++tt) {
    // stage tile (concat row: cols 0..63 = hoI, 64..127 = nbr emb)
#pragma unroll
    for (int k = 0; k < 4; ++k) {
      const int u = lane + (k << 6);
      const int r = u >> 4, bb = u & 15;
      *(f16x8*)(sXw + r * 272 + (bb << 4)) = cvt_f16x8(pa[k], pb[k]);
      if (bb == 0) sM[r] = msk[k];
    }
    if (tt < 2) pf(tt + 1);
    // A-frags (lane mrow = row)
    f16x8 a[4];
#pragma unroll
    for (int ks = 0; ks < 4; ++ks)
      a[ks] = *(const f16x8*)(sXw + mrow * 272 + ((ks * 4 + quad) << 4));
    float mk[4];
#pragma unroll
    for (int rg = 0; rg < 4; ++rg) mk[rg] = sM[quad * 4 + rg];
    float tl[4] = {0.f, 0.f, 0.f, 0.f};
#pragma unroll
    for (int nt = 0; nt < 4; ++nt) {
      f32x4 d = {0.f, 0.f, 0.f, 0.f};
      const int n = nt * 16 + mrow;
#pragma unroll
      for (int ks = 0; ks < 4; ++ks) {
        const f16x8 bW = *(const f16x8*)(sW1 + n * 272 + ((ks * 4 + quad) << 4));
        d = __builtin_amdgcn_mfma_f32_16x16x32_f16(a[ks], bW, d, 0, 0, 0);
      }
#pragma unroll
      for (int rg = 0; rg < 4; ++rg) {
        const float h = fmaxf(d[rg] + b1v[nt], 0.f);
        tl[rg] = fmaf(h, w2v[nt], tl[rg]);
      }
    }
    float e[4];
#pragma unroll
    for (int rg = 0; rg < 4; ++rg) {
      float t = tl[rg];
      t += __shfl_xor(t, 1); t += __shfl_xor(t, 2);
      t += __shfl_xor(t, 4); t += __shfl_xor(t, 8);
      e[rg] = __expf(t + b2s) * mk[rg];
      pden += e[rg];
    }
    if (mrow == 0) {
#pragma unroll
      for (int rg = 0; rg < 4; ++rg) sE[quad * 4 + rg] = e[rg];
    }
    // numer over this tile: lane = col j of hoI
#pragma unroll 4
    for (int r = 0; r < 16; ++r) {
      const float er = sE[r];
      const float xv = (float)*(const _Float16*)(sXw + r * 272 + ((lane >> 3) << 4) +
                                                 ((lane & 7) << 1));
      numer = fmaf(er, xv, numer);
    }
  }
  pden += __shfl_xor(pden, 16);
  pden += __shfl_xor(pden, 32);
  const float hagg = numer / (pden + EPSV);

  // ---- matvec tail (wave-local; weights L2-hot coalesced) ----
  sB[128 + lane] = hagg;
  sB[lane] = hiI[(size_t)b * 64 + lane];
  float acc = aggn_b[lane];
#pragma unroll 8
  for (int k = 0; k < 64; ++k) acc = fmaf(sB[128 + k], aggn_W[k * 64 + lane], acc);
  sB[64 + lane] = fmaxf(acc, 0.f);
  float c1 = cm_b1[lane];
#pragma unroll 8
  for (int k = 0; k < 128; ++k) c1 = fmaf(sB[k], cm_W1[k * 64 + lane], c1);
  sB[128 + lane] = fmaxf(c1, 0.f);
  float c2 = cm_b2[lane];
#pragma unroll 8
  for (int k = 0; k < 64; ++k) c2 = fmaf(sB[128 + k], cm_W2[k * 64 + lane], c2);
  sB[lane] = fmaxf(c2, 0.f);
  float c3 = cm_b3[lane];
#pragma unroll 8
  for (int k = 0; k < 64; ++k) c3 = fmaf(sB[k], cm_W3[k * 64 + lane], c3);
  out[(size_t)b * 64 + lane] = fmaxf(c3, 0.f);
}

extern "C" void kernel_launch(void* const* d_in, const int* in_sizes, int n_in,
                              void* d_out, int out_size, void* d_ws, size_t ws_size,
                              hipStream_t stream) {
  const int* uids = (const int*)d_in[0];
  const int* u_item_pad = (const int*)d_in[1];
  const int* u_user_pad = (const int*)d_in[2];
  const int* u_user_item_pad = (const int*)d_in[3];
  const float* user_table = (const float*)d_in[4];
  const float* item_table = (const float*)d_in[5];
  const float* rate_table = (const float*)d_in[6];
  const float* gv_W1 = (const float*)d_in[7];
  const float* gv_b1 = (const float*)d_in[8];
  const float* gv_W2 = (const float*)d_in[9];
  const float* gv_b2 = (const float*)d_in[10];
  const float* atti_W1 = (const float*)d_in[11];
  const float* atti_b1 = (const float*)d_in[12];
  const float* atti_W2 = (const float*)d_in[13];
  const float* atti_b2 = (const float*)d_in[14];
  const float* agg_W = (const float*)d_in[15];
  const float* agg_b = (const float*)d_in[16];
  const float* attu_W1 = (const float*)d_in[17];
  const float* attu_b1 = (const float*)d_in[18];
  const float* attu_W2 = (const float*)d_in[19];
  const float* attu_b2 = (const float*)d_in[20];
  const float* aggn_W = (const float*)d_in[21];
  const float* aggn_b = (const float*)d_in[22];
  const float* cm_W1 = (const float*)d_in[23];
  const float* cm_b1 = (const float*)d_in[24];
  const float* cm_W2 = (const float*)d_in[25];
  const float* cm_b2 = (const float*)d_in[26];
  const float* cm_W3 = (const float*)d_in[27];
  const float* cm_b3 = (const float*)d_in[28];
  float* out = (float*)d_out;

  float* hoI = (float*)d_ws;                 // 512*40*64 floats
  float* hiI = hoI + (size_t)512 * 40 * 64;  // 512*64 floats

  // Merged S (1280 blocks x 16 groups) + I (128 blocks x 4 groups).
  agg_kernel<<<1280 + 128, 256, 0, stream>>>(
      1280, u_user_item_pad, u_user_pad, u_item_pad, uids,
      user_table, item_table, rate_table,
      gv_W1, gv_b1, gv_W2, gv_b2,
      atti_W1, atti_b1, atti_W2, atti_b2,
      agg_W, agg_b, hoI, hiI);
  // Beta attention + h_iS + final MLP (wave-autonomous MFMA).
  stage2_kernel<<<256, 128, 0, stream>>>(u_user_pad, user_table, hoI, hiI,
                                         attu_W1, attu_b1, attu_W2, attu_b2,
                                         aggn_W, aggn_b,
                                         cm_W1, cm_b1, cm_W2, cm_b2, cm_W3, cm_b3,
                                         out);
}